// Round 1
// baseline (784.363 us; speedup 1.0000x reference)
//
#include <hip/hip_runtime.h>
#include <hip/hip_bf16.h>
#include <math.h>

#define S_LEN 2048
#define DMODEL 1024
#define NHEAD 16
#define HDIM 64

typedef __attribute__((ext_vector_type(8))) short bf16x8;
typedef __attribute__((ext_vector_type(4))) float f32x4;
typedef __attribute__((ext_vector_type(8))) unsigned short u16x8;

#define GLOAD_LDS16(g, l)                                                      \
  __builtin_amdgcn_global_load_lds(                                            \
      (const __attribute__((address_space(1))) void*)(g),                      \
      (__attribute__((address_space(3))) void*)(l), 16, 0, 0)

static __device__ __forceinline__ unsigned short f2bf(float f) {
  union { float f; unsigned int i; } u; u.f = f;
  unsigned int r = u.i + 0x7fff + ((u.i >> 16) & 1);
  return (unsigned short)(r >> 16);
}

// ---------------- weight transpose + cast: W[K][N] f32 -> Wt[N][K] bf16 ----
__global__ __launch_bounds__(256) void wtrans_kernel(const float* __restrict__ W,
                                                     unsigned short* __restrict__ Wt,
                                                     int K, int N) {
  __shared__ float tile[32][33];
  int tx = threadIdx.x, ty = threadIdx.y;
  int n0 = blockIdx.x * 32, k0 = blockIdx.y * 32;
#pragma unroll
  for (int i = 0; i < 4; ++i)
    tile[ty * 4 + i][tx] = W[(size_t)(k0 + ty * 4 + i) * N + n0 + tx];
  __syncthreads();
#pragma unroll
  for (int i = 0; i < 4; ++i)
    Wt[(size_t)(n0 + ty * 4 + i) * K + k0 + tx] = f2bf(tile[tx][ty * 4 + i]);
}

// ---------------- LayerNorm (fp32 in) -> bf16 out -------------------------
__global__ __launch_bounds__(256) void ln_kernel(const float* __restrict__ X,
                                                 const float* __restrict__ w,
                                                 const float* __restrict__ b,
                                                 unsigned short* __restrict__ out) {
  int row = blockIdx.x;
  int t = threadIdx.x;
  const float4* xr = (const float4*)(X + (size_t)row * DMODEL);
  float4 v = xr[t];
  float s = v.x + v.y + v.z + v.w;
  float q = v.x * v.x + v.y * v.y + v.z * v.z + v.w * v.w;
#pragma unroll
  for (int m = 1; m < 64; m <<= 1) {
    s += __shfl_xor(s, m, 64);
    q += __shfl_xor(q, m, 64);
  }
  __shared__ float red[8];
  int wv = t >> 6;
  if ((t & 63) == 0) { red[wv] = s; red[4 + wv] = q; }
  __syncthreads();
  s = red[0] + red[1] + red[2] + red[3];
  q = red[4] + red[5] + red[6] + red[7];
  float mu = s * (1.0f / DMODEL);
  float var = q * (1.0f / DMODEL) - mu * mu;
  float rs = rsqrtf(var + 1e-5f);
  float4 wv4 = ((const float4*)w)[t];
  float4 bv4 = ((const float4*)b)[t];
  ushort4 o;
  o.x = f2bf((v.x - mu) * rs * wv4.x + bv4.x);
  o.y = f2bf((v.y - mu) * rs * wv4.y + bv4.y);
  o.z = f2bf((v.z - mu) * rs * wv4.z + bv4.z);
  o.w = f2bf((v.w - mu) * rs * wv4.w + bv4.w);
  ((ushort4*)(out + (size_t)row * DMODEL))[t] = o;
}

// ---------------- GEMM: A[M][K] bf16 x Bt[N][K] bf16, fp32 acc ------------
// EPI: 0 = QKV scatter (q,k,v bf16 [B,H,S,64])
//      1 = fp32 out = acc + bias + extra (residual)
//      2 = bf16 out = gelu(acc + bias), stride N
//      3 = fp32 out = acc + bias + extra
template <int EPI>
__global__ __launch_bounds__(256) void gemm_kernel(
    const unsigned short* __restrict__ A, const unsigned short* __restrict__ Bt,
    const float* __restrict__ bias, int N, int K,
    void* __restrict__ o0, void* __restrict__ o1, void* __restrict__ o2,
    const float* __restrict__ extra) {
  __shared__ __align__(16) unsigned short sA[128 * 32];
  __shared__ __align__(16) unsigned short sB[128 * 32];
  const int t = threadIdx.x;
  const int w = t >> 6, lane = t & 63;
  const int wr = w >> 1, wc = w & 1;
  const int m0 = blockIdx.y * 128, n0 = blockIdx.x * 128;

  const int o0b = w * 2048 + lane * 16;
  const int o1b = o0b + 1024;
  const char* gA0 = (const char*)A + (size_t)(m0 + (o0b >> 6)) * K * 2 + (o0b & 63);
  const char* gA1 = (const char*)A + (size_t)(m0 + (o1b >> 6)) * K * 2 + (o1b & 63);
  const char* gB0 = (const char*)Bt + (size_t)(n0 + (o0b >> 6)) * K * 2 + (o0b & 63);
  const char* gB1 = (const char*)Bt + (size_t)(n0 + (o1b >> 6)) * K * 2 + (o1b & 63);
  char* lA = (char*)sA + w * 2048;
  char* lB = (char*)sB + w * 2048;

  f32x4 acc[4][4] = {};
  const int lc = lane & 15, lh = lane >> 4;
  const int aoff = (wr * 64 + lc) * 32 + lh * 8;
  const int boff = (wc * 64 + lc) * 32 + lh * 8;

  for (int k0 = 0; k0 < K; k0 += 32) {
    __syncthreads();
    GLOAD_LDS16(gA0 + (size_t)k0 * 2, lA);
    GLOAD_LDS16(gA1 + (size_t)k0 * 2, lA + 1024);
    GLOAD_LDS16(gB0 + (size_t)k0 * 2, lB);
    GLOAD_LDS16(gB1 + (size_t)k0 * 2, lB + 1024);
    __syncthreads();
    bf16x8 af[4], bg[4];
#pragma unroll
    for (int i = 0; i < 4; ++i) af[i] = *(const bf16x8*)(sA + aoff + i * 16 * 32);
#pragma unroll
    for (int i = 0; i < 4; ++i) bg[i] = *(const bf16x8*)(sB + boff + i * 16 * 32);
#pragma unroll
    for (int i = 0; i < 4; ++i)
#pragma unroll
      for (int j = 0; j < 4; ++j)
        acc[i][j] = __builtin_amdgcn_mfma_f32_16x16x32_bf16(af[i], bg[j], acc[i][j], 0, 0, 0);
  }

#pragma unroll
  for (int i = 0; i < 4; ++i)
#pragma unroll
    for (int j = 0; j < 4; ++j) {
      int col = n0 + wc * 64 + j * 16 + lc;
      float bcol = bias[col];
#pragma unroll
      for (int r = 0; r < 4; ++r) {
        int row = m0 + wr * 64 + i * 16 + lh * 4 + r;
        float val = acc[i][j][r] + bcol;
        if constexpr (EPI == 0) {
          int bb = row >> 11, srow = row & 2047;
          int hh = col / 192, rem = col - hh * 192;
          int which = rem >> 6, a = rem & 63;
          unsigned short* dst =
              which == 0 ? (unsigned short*)o0 : which == 1 ? (unsigned short*)o1 : (unsigned short*)o2;
          dst[(((size_t)bb * NHEAD + hh) * S_LEN + srow) * HDIM + a] = f2bf(val);
        } else if constexpr (EPI == 2) {
          float g = 0.5f * val * (1.0f + erff(val * 0.70710678118654752f));
          ((unsigned short*)o0)[(size_t)row * N + col] = f2bf(g);
        } else {
          size_t idx = (size_t)row * DMODEL + col;
          ((float*)o0)[idx] = val + extra[idx];
        }
      }
    }
}

// ---------------- causal flash attention, bf16, per-(b,h) -----------------
__global__ __launch_bounds__(256) void attn_kernel(
    const unsigned short* __restrict__ Q, const unsigned short* __restrict__ Kk,
    const unsigned short* __restrict__ V, unsigned short* __restrict__ ctx) {
  __shared__ __align__(16) unsigned short sK[64 * 64];       // swizzled, rows of 128B
  __shared__ __align__(16) unsigned short sVt[64 * 72];      // V^T, padded
  __shared__ __align__(16) unsigned short sP[4][16 * 72];    // per-wave P

  const int qblk = blockIdx.x;   // 0..31
  const int bh = blockIdx.y;     // 0..63
  const int t = threadIdx.x;
  const int w = t >> 6, lane = t & 63;
  const int lc = lane & 15, lh = lane >> 4;
  const int q0 = qblk * 64;
  const size_t base = (size_t)bh * S_LEN * HDIM;
  const unsigned short* Qb = Q + base;
  const unsigned short* Kb = Kk + base;
  const unsigned short* Vb = V + base;

  const int qrow = q0 + w * 16 + lc;
  bf16x8 qf[2];
  qf[0] = *(const bf16x8*)(Qb + (size_t)qrow * HDIM + lh * 8);
  qf[1] = *(const bf16x8*)(Qb + (size_t)qrow * HDIM + 32 + lh * 8);

  f32x4 acc[4] = {};
  float mrow[4], lrow[4];
#pragma unroll
  for (int r = 0; r < 4; ++r) { mrow[r] = -INFINITY; lrow[r] = 0.f; }

  const int vr = t >> 2, vc0 = (t & 3) * 16;

  for (int tile = 0; tile <= qblk; ++tile) {
    const int kv0 = tile * 64;
    __syncthreads();
    {  // K stage: pre-swizzled global source, linear LDS dest (rule #21)
      const char* Ks = (const char*)(Kb + (size_t)kv0 * HDIM);
#pragma unroll
      for (int c = 0; c < 2; ++c) {
        int o = w * 2048 + c * 1024 + lane * 16;
        int row = o >> 7, cb = o & 127;
        int cbs = cb ^ ((row & 7) << 4);
        GLOAD_LDS16(Ks + row * 128 + cbs, (char*)sK + w * 2048 + c * 1024);
      }
    }
    {  // V^T stage via registers into padded LDS
      const unsigned short* Vs = Vb + (size_t)kv0 * HDIM;
      u16x8 v0 = *(const u16x8*)(Vs + vr * 64 + vc0);
      u16x8 v1 = *(const u16x8*)(Vs + vr * 64 + vc0 + 8);
#pragma unroll
      for (int j = 0; j < 8; ++j) sVt[(vc0 + j) * 72 + vr] = (unsigned short)v0[j];
#pragma unroll
      for (int j = 0; j < 8; ++j) sVt[(vc0 + 8 + j) * 72 + vr] = (unsigned short)v1[j];
    }
    __syncthreads();

    // scores S = Q K^T
    f32x4 s[4] = {};
#pragma unroll
    for (int f = 0; f < 4; ++f) {
      int row = f * 16 + lc;
      int swz = (row & 7) << 4;
#pragma unroll
      for (int kk = 0; kk < 2; ++kk) {
        int cb = kk * 64 + lh * 16;
        bf16x8 kf = *(const bf16x8*)((const char*)sK + row * 128 + (cb ^ swz));
        s[f] = __builtin_amdgcn_mfma_f32_16x16x32_bf16(qf[kk], kf, s[f], 0, 0, 0);
      }
    }
    const bool diag = (tile == qblk);
#pragma unroll
    for (int f = 0; f < 4; ++f)
#pragma unroll
      for (int r = 0; r < 4; ++r) {
        float sv = s[f][r] * 0.125f;
        if (diag && (f * 16 + lc > w * 16 + lh * 4 + r)) sv = -INFINITY;
        s[f][r] = sv;
      }
    // online softmax (16-lane-group row reductions)
    float alpha[4];
#pragma unroll
    for (int r = 0; r < 4; ++r) {
      float mv = fmaxf(fmaxf(s[0][r], s[1][r]), fmaxf(s[2][r], s[3][r]));
#pragma unroll
      for (int msk = 1; msk < 16; msk <<= 1) mv = fmaxf(mv, __shfl_xor(mv, msk, 64));
      float mnew = fmaxf(mrow[r], mv);
      alpha[r] = expf(mrow[r] - mnew);
      mrow[r] = mnew;
    }
#pragma unroll
    for (int r = 0; r < 4; ++r) {
      float ps = 0.f;
#pragma unroll
      for (int f = 0; f < 4; ++f) {
        float p = expf(s[f][r] - mrow[r]);
        s[f][r] = p;
        ps += p;
      }
#pragma unroll
      for (int msk = 1; msk < 16; msk <<= 1) ps += __shfl_xor(ps, msk, 64);
      lrow[r] = lrow[r] * alpha[r] + ps;
#pragma unroll
      for (int f = 0; f < 4; ++f) acc[f][r] *= alpha[r];
    }
    // P: C-layout -> A-frag layout via per-wave LDS
    unsigned short* Pw = &sP[w][0];
#pragma unroll
    for (int f = 0; f < 4; ++f)
#pragma unroll
      for (int r = 0; r < 4; ++r)
        Pw[(lh * 4 + r) * 72 + f * 16 + lc] = f2bf(s[f][r]);
    bf16x8 pa[2];
#pragma unroll
    for (int kk = 0; kk < 2; ++kk)
      pa[kk] = *(const bf16x8*)(Pw + lc * 72 + kk * 32 + lh * 8);
#pragma unroll
    for (int f = 0; f < 4; ++f)
#pragma unroll
      for (int kk = 0; kk < 2; ++kk) {
        bf16x8 bv = *(const bf16x8*)(sVt + (f * 16 + lc) * 72 + kk * 32 + lh * 8);
        acc[f] = __builtin_amdgcn_mfma_f32_16x16x32_bf16(pa[kk], bv, acc[f], 0, 0, 0);
      }
  }
  const int b = bh >> 4, h = bh & 15;
#pragma unroll
  for (int f = 0; f < 4; ++f)
#pragma unroll
    for (int r = 0; r < 4; ++r) {
      int qg = q0 + w * 16 + lh * 4 + r;
      float ov = acc[f][r] / lrow[r];
      ctx[((size_t)b * S_LEN + qg) * DMODEL + h * HDIM + f * 16 + lc] = f2bf(ov);
    }
}

// ---------------- launch --------------------------------------------------
extern "C" void kernel_launch(void* const* d_in, const int* in_sizes, int n_in,
                              void* d_out, int out_size, void* d_ws, size_t ws_size,
                              hipStream_t stream) {
  const float* x    = (const float*)d_in[0];
  const float* ln1w = (const float*)d_in[1];
  const float* ln1b = (const float*)d_in[2];
  const float* ln2w = (const float*)d_in[3];
  const float* ln2b = (const float*)d_in[4];
  const float* Wqkv = (const float*)d_in[5];
  const float* bqkv = (const float*)d_in[6];
  const float* Wo   = (const float*)d_in[7];
  const float* bo   = (const float*)d_in[8];
  const float* Wup  = (const float*)d_in[9];
  const float* bup  = (const float*)d_in[10];
  const float* Wdn  = (const float*)d_in[11];
  const float* bdn  = (const float*)d_in[12];

  char* ws = (char*)d_ws;
  // aliased layout (lifetimes don't overlap): total 142,606,336 B
  unsigned short* xn  = (unsigned short*)(ws + 0);          // 16 MiB, dead after QKV gemm
  unsigned short* qb  = (unsigned short*)(ws + 16777216);   // 16 MiB
  unsigned short* kb  = (unsigned short*)(ws + 33554432);   // 16 MiB
  unsigned short* vb  = (unsigned short*)(ws + 50331648);   // 16 MiB  (q/k/v dead after attn)
  unsigned short* hb  = (unsigned short*)(ws + 0);          // 64 MiB, aliases xn+q/k/v
  unsigned short* ctx = (unsigned short*)(ws + 67108864);   // 16 MiB, dead after O gemm
  unsigned short* hn  = (unsigned short*)(ws + 67108864);   // aliases ctx
  float* attn         = (float*)(ws + 83886080);            // 32 MiB, live to end
  unsigned short* WtQKV = (unsigned short*)(ws + 117440512);
  unsigned short* WtO   = (unsigned short*)(ws + 123731968);
  unsigned short* WtUP  = (unsigned short*)(ws + 125829120);
  unsigned short* WtDN  = (unsigned short*)(ws + 134217728);

  dim3 tb(32, 8);
  wtrans_kernel<<<dim3(3072 / 32, 1024 / 32), tb, 0, stream>>>(Wqkv, WtQKV, 1024, 3072);
  wtrans_kernel<<<dim3(1024 / 32, 1024 / 32), tb, 0, stream>>>(Wo, WtO, 1024, 1024);
  wtrans_kernel<<<dim3(4096 / 32, 1024 / 32), tb, 0, stream>>>(Wup, WtUP, 1024, 4096);
  wtrans_kernel<<<dim3(1024 / 32, 4096 / 32), tb, 0, stream>>>(Wdn, WtDN, 4096, 1024);

  ln_kernel<<<8192, 256, 0, stream>>>(x, ln1w, ln1b, xn);

  gemm_kernel<0><<<dim3(3072 / 128, 8192 / 128), 256, 0, stream>>>(
      xn, WtQKV, bqkv, 3072, 1024, qb, kb, vb, nullptr);

  attn_kernel<<<dim3(32, 64), 256, 0, stream>>>(qb, kb, vb, ctx);

  gemm_kernel<1><<<dim3(1024 / 128, 8192 / 128), 256, 0, stream>>>(
      ctx, WtO, bo, 1024, 1024, attn, nullptr, nullptr, x);

  ln_kernel<<<8192, 256, 0, stream>>>(attn, ln2w, ln2b, hn);

  gemm_kernel<2><<<dim3(4096 / 128, 8192 / 128), 256, 0, stream>>>(
      hn, WtUP, bup, 4096, 1024, hb, nullptr, nullptr, nullptr);

  gemm_kernel<3><<<dim3(1024 / 128, 8192 / 128), 256, 0, stream>>>(
      hb, WtDN, bdn, 1024, 4096, d_out, nullptr, nullptr, attn);
}

// Round 2
// 716.577 us; speedup vs baseline: 1.0946x; 1.0946x over previous
//
#include <hip/hip_runtime.h>
#include <hip/hip_bf16.h>
#include <math.h>

#define S_LEN 2048
#define DMODEL 1024
#define NHEAD 16
#define HDIM 64

typedef __attribute__((ext_vector_type(8))) short bf16x8;
typedef __attribute__((ext_vector_type(4))) float f32x4;
typedef __attribute__((ext_vector_type(8))) unsigned short u16x8;

#define GLOAD_LDS16(g, l)                                                      \
  __builtin_amdgcn_global_load_lds(                                            \
      (const __attribute__((address_space(1))) void*)(g),                      \
      (__attribute__((address_space(3))) void*)(l), 16, 0, 0)

static __device__ __forceinline__ unsigned short f2bf(float f) {
  union { float f; unsigned int i; } u; u.f = f;
  unsigned int r = u.i + 0x7fff + ((u.i >> 16) & 1);
  return (unsigned short)(r >> 16);
}

// ---------------- weight transpose + cast: W[K][N] f32 -> Wt[N][K] bf16 ----
__global__ __launch_bounds__(256) void wtrans_kernel(const float* __restrict__ W,
                                                     unsigned short* __restrict__ Wt,
                                                     int K, int N) {
  __shared__ float tile[32][33];
  int tx = threadIdx.x, ty = threadIdx.y;
  int n0 = blockIdx.x * 32, k0 = blockIdx.y * 32;
#pragma unroll
  for (int i = 0; i < 4; ++i)
    tile[ty * 4 + i][tx] = W[(size_t)(k0 + ty * 4 + i) * N + n0 + tx];
  __syncthreads();
#pragma unroll
  for (int i = 0; i < 4; ++i)
    Wt[(size_t)(n0 + ty * 4 + i) * K + k0 + tx] = f2bf(tile[tx][ty * 4 + i]);
}

// ---------------- LayerNorm (fp32 in) -> bf16 out -------------------------
__global__ __launch_bounds__(256) void ln_kernel(const float* __restrict__ X,
                                                 const float* __restrict__ w,
                                                 const float* __restrict__ b,
                                                 unsigned short* __restrict__ out) {
  int row = blockIdx.x;
  int t = threadIdx.x;
  const float4* xr = (const float4*)(X + (size_t)row * DMODEL);
  float4 v = xr[t];
  float s = v.x + v.y + v.z + v.w;
  float q = v.x * v.x + v.y * v.y + v.z * v.z + v.w * v.w;
#pragma unroll
  for (int m = 1; m < 64; m <<= 1) {
    s += __shfl_xor(s, m, 64);
    q += __shfl_xor(q, m, 64);
  }
  __shared__ float red[8];
  int wv = t >> 6;
  if ((t & 63) == 0) { red[wv] = s; red[4 + wv] = q; }
  __syncthreads();
  s = red[0] + red[1] + red[2] + red[3];
  q = red[4] + red[5] + red[6] + red[7];
  float mu = s * (1.0f / DMODEL);
  float var = q * (1.0f / DMODEL) - mu * mu;
  float rs = rsqrtf(var + 1e-5f);
  float4 wv4 = ((const float4*)w)[t];
  float4 bv4 = ((const float4*)b)[t];
  ushort4 o;
  o.x = f2bf((v.x - mu) * rs * wv4.x + bv4.x);
  o.y = f2bf((v.y - mu) * rs * wv4.y + bv4.y);
  o.z = f2bf((v.z - mu) * rs * wv4.z + bv4.z);
  o.w = f2bf((v.w - mu) * rs * wv4.w + bv4.w);
  ((ushort4*)(out + (size_t)row * DMODEL))[t] = o;
}

// ---------------- GEMM: A[M][K] bf16 x Bt[N][K] bf16, fp32 acc ------------
template <int EPI>
__global__ __launch_bounds__(256) void gemm_kernel(
    const unsigned short* __restrict__ A, const unsigned short* __restrict__ Bt,
    const float* __restrict__ bias, int N, int K,
    void* __restrict__ o0, void* __restrict__ o1, void* __restrict__ o2,
    const float* __restrict__ extra) {
  __shared__ __align__(16) unsigned short sA[128 * 32];
  __shared__ __align__(16) unsigned short sB[128 * 32];
  const int t = threadIdx.x;
  const int w = t >> 6, lane = t & 63;
  const int wr = w >> 1, wc = w & 1;

  // T1: bijective XCD-aware swizzle (m204); all grids here have nwg % 8 == 0
  const int gx = gridDim.x;
  const int nwg = gx * gridDim.y;
  int bid = blockIdx.y * gx + blockIdx.x;
  {
    int xcd = bid & 7, pos = bid >> 3;
    int qq = nwg >> 3, rr = nwg & 7;
    bid = (xcd < rr ? xcd * (qq + 1) : rr * (qq + 1) + (xcd - rr) * qq) + pos;
  }
  const int m0 = (bid / gx) * 128, n0 = (bid % gx) * 128;

  const int o0b = w * 2048 + lane * 16;
  const int o1b = o0b + 1024;
  const char* gA0 = (const char*)A + (size_t)(m0 + (o0b >> 6)) * K * 2 + (o0b & 63);
  const char* gA1 = (const char*)A + (size_t)(m0 + (o1b >> 6)) * K * 2 + (o1b & 63);
  const char* gB0 = (const char*)Bt + (size_t)(n0 + (o0b >> 6)) * K * 2 + (o0b & 63);
  const char* gB1 = (const char*)Bt + (size_t)(n0 + (o1b >> 6)) * K * 2 + (o1b & 63);
  char* lA = (char*)sA + w * 2048;
  char* lB = (char*)sB + w * 2048;

  f32x4 acc[4][4] = {};
  const int lc = lane & 15, lh = lane >> 4;
  const int aoff = (wr * 64 + lc) * 32 + lh * 8;
  const int boff = (wc * 64 + lc) * 32 + lh * 8;

  for (int k0 = 0; k0 < K; k0 += 32) {
    __syncthreads();
    GLOAD_LDS16(gA0 + (size_t)k0 * 2, lA);
    GLOAD_LDS16(gA1 + (size_t)k0 * 2, lA + 1024);
    GLOAD_LDS16(gB0 + (size_t)k0 * 2, lB);
    GLOAD_LDS16(gB1 + (size_t)k0 * 2, lB + 1024);
    __syncthreads();
    bf16x8 af[4], bg[4];
#pragma unroll
    for (int i = 0; i < 4; ++i) af[i] = *(const bf16x8*)(sA + aoff + i * 16 * 32);
#pragma unroll
    for (int i = 0; i < 4; ++i) bg[i] = *(const bf16x8*)(sB + boff + i * 16 * 32);
#pragma unroll
    for (int i = 0; i < 4; ++i)
#pragma unroll
      for (int j = 0; j < 4; ++j)
        acc[i][j] = __builtin_amdgcn_mfma_f32_16x16x32_bf16(af[i], bg[j], acc[i][j], 0, 0, 0);
  }

#pragma unroll
  for (int i = 0; i < 4; ++i)
#pragma unroll
    for (int j = 0; j < 4; ++j) {
      int col = n0 + wc * 64 + j * 16 + lc;
      float bcol = bias[col];
#pragma unroll
      for (int r = 0; r < 4; ++r) {
        int row = m0 + wr * 64 + i * 16 + lh * 4 + r;
        float val = acc[i][j][r] + bcol;
        if constexpr (EPI == 0) {
          int bb = row >> 11, srow = row & 2047;
          int hh = col / 192, rem = col - hh * 192;
          int which = rem >> 6, a = rem & 63;
          unsigned short* dst =
              which == 0 ? (unsigned short*)o0 : which == 1 ? (unsigned short*)o1 : (unsigned short*)o2;
          dst[(((size_t)bb * NHEAD + hh) * S_LEN + srow) * HDIM + a] = f2bf(val);
        } else if constexpr (EPI == 2) {
          float g = 0.5f * val * (1.0f + erff(val * 0.70710678118654752f));
          ((unsigned short*)o0)[(size_t)row * N + col] = f2bf(g);
        } else {
          size_t idx = (size_t)row * DMODEL + col;
          ((float*)o0)[idx] = val + extra[idx];
        }
      }
    }
}

// ---------------- causal flash attention, bf16, paired q-tiles ------------
// Block pi handles q-tiles {pi, 31-pi}: balanced 33 compute-units/block,
// K/V staged once for both. Softmax in exp2 domain.
__global__ __launch_bounds__(256, 4) void attn_kernel(
    const unsigned short* __restrict__ Q, const unsigned short* __restrict__ Kk,
    const unsigned short* __restrict__ V, unsigned short* __restrict__ ctx) {
  __shared__ __align__(16) unsigned short sK[64 * 64];     // swizzled rows of 128B
  __shared__ __align__(16) unsigned short sVt[64 * 72];    // V^T, padded
  __shared__ __align__(16) unsigned short sP[4][16 * 72];  // per-wave P

  const int pi = blockIdx.x;     // 0..15
  const int bh = blockIdx.y;     // 0..63
  const int t = threadIdx.x;
  const int w = t >> 6, lane = t & 63;
  const int lc = lane & 15, lh = lane >> 4;
  const int qtA = pi, qtB = 31 - pi;
  const size_t base = (size_t)bh * S_LEN * HDIM;
  const unsigned short* Qb = Q + base;
  const unsigned short* Kb = Kk + base;
  const unsigned short* Vb = V + base;

  bf16x8 qfA[2], qfB[2];
  {
    const unsigned short* qa = Qb + (size_t)(qtA * 64 + w * 16 + lc) * HDIM;
    const unsigned short* qb = Qb + (size_t)(qtB * 64 + w * 16 + lc) * HDIM;
    qfA[0] = *(const bf16x8*)(qa + lh * 8);
    qfA[1] = *(const bf16x8*)(qa + 32 + lh * 8);
    qfB[0] = *(const bf16x8*)(qb + lh * 8);
    qfB[1] = *(const bf16x8*)(qb + 32 + lh * 8);
  }

  f32x4 accA[4] = {}, accB[4] = {};
  float mA[4], lA[4], mB[4], lB[4];
#pragma unroll
  for (int r = 0; r < 4; ++r) { mA[r] = -INFINITY; lA[r] = 0.f; mB[r] = -INFINITY; lB[r] = 0.f; }

  const float SCL = 0.125f * 1.44269504088896f;  // exp2 domain

  auto process = [&](const bf16x8 (&qf)[2], f32x4 (&acc)[4], float (&mrow)[4],
                     float (&lrow)[4], bool diag) {
    f32x4 s[4] = {};
    __builtin_amdgcn_s_setprio(1);
#pragma unroll
    for (int f = 0; f < 4; ++f) {
      int row = f * 16 + lc;
      int swz = (row & 7) << 4;
#pragma unroll
      for (int kk = 0; kk < 2; ++kk) {
        int cb = kk * 64 + lh * 16;
        bf16x8 kf = *(const bf16x8*)((const char*)sK + row * 128 + (cb ^ swz));
        s[f] = __builtin_amdgcn_mfma_f32_16x16x32_bf16(qf[kk], kf, s[f], 0, 0, 0);
      }
    }
    __builtin_amdgcn_s_setprio(0);
#pragma unroll
    for (int f = 0; f < 4; ++f)
#pragma unroll
      for (int r = 0; r < 4; ++r) {
        float sv = s[f][r] * SCL;
        if (diag && (f * 16 + lc > w * 16 + lh * 4 + r)) sv = -INFINITY;
        s[f][r] = sv;
      }
    float alpha[4];
#pragma unroll
    for (int r = 0; r < 4; ++r) {
      float mv = fmaxf(fmaxf(s[0][r], s[1][r]), fmaxf(s[2][r], s[3][r]));
#pragma unroll
      for (int msk = 1; msk < 16; msk <<= 1) mv = fmaxf(mv, __shfl_xor(mv, msk, 64));
      float mnew = fmaxf(mrow[r], mv);
      alpha[r] = __builtin_amdgcn_exp2f(mrow[r] - mnew);
      mrow[r] = mnew;
    }
#pragma unroll
    for (int r = 0; r < 4; ++r) {
      float ps = 0.f;
#pragma unroll
      for (int f = 0; f < 4; ++f) {
        float p = __builtin_amdgcn_exp2f(s[f][r] - mrow[r]);
        s[f][r] = p;
        ps += p;
      }
#pragma unroll
      for (int msk = 1; msk < 16; msk <<= 1) ps += __shfl_xor(ps, msk, 64);
      lrow[r] = lrow[r] * alpha[r] + ps;
#pragma unroll
      for (int f = 0; f < 4; ++f) acc[f][r] *= alpha[r];
    }
    unsigned short* Pw = &sP[w][0];
#pragma unroll
    for (int f = 0; f < 4; ++f)
#pragma unroll
      for (int r = 0; r < 4; ++r)
        Pw[(lh * 4 + r) * 72 + f * 16 + lc] = f2bf(s[f][r]);
    bf16x8 pa[2];
#pragma unroll
    for (int kk = 0; kk < 2; ++kk)
      pa[kk] = *(const bf16x8*)(Pw + lc * 72 + kk * 32 + lh * 8);
    __builtin_amdgcn_s_setprio(1);
#pragma unroll
    for (int f = 0; f < 4; ++f)
#pragma unroll
      for (int kk = 0; kk < 2; ++kk) {
        bf16x8 bv = *(const bf16x8*)(sVt + (f * 16 + lc) * 72 + kk * 32 + lh * 8);
        acc[f] = __builtin_amdgcn_mfma_f32_16x16x32_bf16(pa[kk], bv, acc[f], 0, 0, 0);
      }
    __builtin_amdgcn_s_setprio(0);
  };

  for (int tile = 0; tile <= qtB; ++tile) {
    const int kv0 = tile * 64;
    __syncthreads();
    {  // K stage: pre-swizzled global source, linear LDS dest (rule #21)
      const char* Ks = (const char*)(Kb + (size_t)kv0 * HDIM);
#pragma unroll
      for (int c = 0; c < 2; ++c) {
        int o = w * 2048 + c * 1024 + lane * 16;
        int row = o >> 7, cb = o & 127;
        int cbs = cb ^ ((row & 7) << 4);
        GLOAD_LDS16(Ks + row * 128 + cbs, (char*)sK + w * 2048 + c * 1024);
      }
    }
    {  // V^T stage: each wave owns d-block w*16, lanes sweep kv -> conflict-free
      const unsigned short* Vs = Vb + (size_t)kv0 * HDIM;
      const int d0 = w * 16;
      u16x8 v0 = *(const u16x8*)(Vs + (size_t)lane * HDIM + d0);
      u16x8 v1 = *(const u16x8*)(Vs + (size_t)lane * HDIM + d0 + 8);
#pragma unroll
      for (int j = 0; j < 8; ++j) sVt[(d0 + j) * 72 + lane] = (unsigned short)v0[j];
#pragma unroll
      for (int j = 0; j < 8; ++j) sVt[(d0 + 8 + j) * 72 + lane] = (unsigned short)v1[j];
    }
    __syncthreads();

    process(qfB, accB, mB, lB, tile == qtB);
    if (tile <= qtA) process(qfA, accA, mA, lA, tile == qtA);
  }

  const int b = bh >> 4, h = bh & 15;
  auto writeout = [&](int qt, f32x4 (&acc)[4], float (&lrow)[4]) {
#pragma unroll
    for (int r = 0; r < 4; ++r) {
      float inv = 1.0f / lrow[r];
      int qg = qt * 64 + w * 16 + lh * 4 + r;
#pragma unroll
      for (int f = 0; f < 4; ++f)
        ctx[((size_t)b * S_LEN + qg) * DMODEL + h * HDIM + f * 16 + lc] = f2bf(acc[f][r] * inv);
    }
  };
  writeout(qtA, accA, lA);
  writeout(qtB, accB, lB);
}

// ---------------- launch --------------------------------------------------
extern "C" void kernel_launch(void* const* d_in, const int* in_sizes, int n_in,
                              void* d_out, int out_size, void* d_ws, size_t ws_size,
                              hipStream_t stream) {
  const float* x    = (const float*)d_in[0];
  const float* ln1w = (const float*)d_in[1];
  const float* ln1b = (const float*)d_in[2];
  const float* ln2w = (const float*)d_in[3];
  const float* ln2b = (const float*)d_in[4];
  const float* Wqkv = (const float*)d_in[5];
  const float* bqkv = (const float*)d_in[6];
  const float* Wo   = (const float*)d_in[7];
  const float* bo   = (const float*)d_in[8];
  const float* Wup  = (const float*)d_in[9];
  const float* bup  = (const float*)d_in[10];
  const float* Wdn  = (const float*)d_in[11];
  const float* bdn  = (const float*)d_in[12];

  char* ws = (char*)d_ws;
  unsigned short* xn  = (unsigned short*)(ws + 0);
  unsigned short* qb  = (unsigned short*)(ws + 16777216);
  unsigned short* kb  = (unsigned short*)(ws + 33554432);
  unsigned short* vb  = (unsigned short*)(ws + 50331648);
  unsigned short* hb  = (unsigned short*)(ws + 0);
  unsigned short* ctx = (unsigned short*)(ws + 67108864);
  unsigned short* hn  = (unsigned short*)(ws + 67108864);
  float* attn         = (float*)(ws + 83886080);
  unsigned short* WtQKV = (unsigned short*)(ws + 117440512);
  unsigned short* WtO   = (unsigned short*)(ws + 123731968);
  unsigned short* WtUP  = (unsigned short*)(ws + 125829120);
  unsigned short* WtDN  = (unsigned short*)(ws + 134217728);

  dim3 tb(32, 8);
  wtrans_kernel<<<dim3(3072 / 32, 1024 / 32), tb, 0, stream>>>(Wqkv, WtQKV, 1024, 3072);
  wtrans_kernel<<<dim3(1024 / 32, 1024 / 32), tb, 0, stream>>>(Wo, WtO, 1024, 1024);
  wtrans_kernel<<<dim3(4096 / 32, 1024 / 32), tb, 0, stream>>>(Wup, WtUP, 1024, 4096);
  wtrans_kernel<<<dim3(1024 / 32, 4096 / 32), tb, 0, stream>>>(Wdn, WtDN, 4096, 1024);

  ln_kernel<<<8192, 256, 0, stream>>>(x, ln1w, ln1b, xn);

  gemm_kernel<0><<<dim3(3072 / 128, 8192 / 128), 256, 0, stream>>>(
      xn, WtQKV, bqkv, 3072, 1024, qb, kb, vb, nullptr);

  attn_kernel<<<dim3(16, 64), 256, 0, stream>>>(qb, kb, vb, ctx);

  gemm_kernel<1><<<dim3(1024 / 128, 8192 / 128), 256, 0, stream>>>(
      ctx, WtO, bo, 1024, 1024, attn, nullptr, nullptr, x);

  ln_kernel<<<8192, 256, 0, stream>>>(attn, ln2w, ln2b, hn);

  gemm_kernel<2><<<dim3(4096 / 128, 8192 / 128), 256, 0, stream>>>(
      hn, WtUP, bup, 4096, 1024, hb, nullptr, nullptr, nullptr);

  gemm_kernel<3><<<dim3(1024 / 128, 8192 / 128), 256, 0, stream>>>(
      hb, WtDN, bdn, 1024, 4096, d_out, nullptr, nullptr, attn);
}

// Round 3
// 628.597 us; speedup vs baseline: 1.2478x; 1.1400x over previous
//
#include <hip/hip_runtime.h>
#include <hip/hip_bf16.h>
#include <math.h>

#define S_LEN 2048
#define DMODEL 1024
#define NHEAD 16
#define HDIM 64

typedef __attribute__((ext_vector_type(8))) short bf16x8;
typedef __attribute__((ext_vector_type(4))) float f32x4;
typedef __attribute__((ext_vector_type(8))) unsigned short u16x8;

#define GLOAD_LDS16(g, l)                                                      \
  __builtin_amdgcn_global_load_lds(                                            \
      (const __attribute__((address_space(1))) void*)(g),                      \
      (__attribute__((address_space(3))) void*)(l), 16, 0, 0)

static __device__ __forceinline__ unsigned short f2bf(float f) {
  union { float f; unsigned int i; } u; u.f = f;
  unsigned int r = u.i + 0x7fff + ((u.i >> 16) & 1);
  return (unsigned short)(r >> 16);
}

// ---------------- weight transpose + cast: W[K][N] f32 -> Wt[N][K] bf16 ----
__global__ __launch_bounds__(256) void wtrans_kernel(const float* __restrict__ W,
                                                     unsigned short* __restrict__ Wt,
                                                     int K, int N) {
  __shared__ float tile[32][33];
  int tx = threadIdx.x, ty = threadIdx.y;
  int n0 = blockIdx.x * 32, k0 = blockIdx.y * 32;
#pragma unroll
  for (int i = 0; i < 4; ++i)
    tile[ty * 4 + i][tx] = W[(size_t)(k0 + ty * 4 + i) * N + n0 + tx];
  __syncthreads();
#pragma unroll
  for (int i = 0; i < 4; ++i)
    Wt[(size_t)(n0 + ty * 4 + i) * K + k0 + tx] = f2bf(tile[tx][ty * 4 + i]);
}

// ---------------- LayerNorm (fp32 in) -> bf16 out -------------------------
__global__ __launch_bounds__(256) void ln_kernel(const float* __restrict__ X,
                                                 const float* __restrict__ w,
                                                 const float* __restrict__ b,
                                                 unsigned short* __restrict__ out) {
  int row = blockIdx.x;
  int t = threadIdx.x;
  const float4* xr = (const float4*)(X + (size_t)row * DMODEL);
  float4 v = xr[t];
  float s = v.x + v.y + v.z + v.w;
  float q = v.x * v.x + v.y * v.y + v.z * v.z + v.w * v.w;
#pragma unroll
  for (int m = 1; m < 64; m <<= 1) {
    s += __shfl_xor(s, m, 64);
    q += __shfl_xor(q, m, 64);
  }
  __shared__ float red[8];
  int wv = t >> 6;
  if ((t & 63) == 0) { red[wv] = s; red[4 + wv] = q; }
  __syncthreads();
  s = red[0] + red[1] + red[2] + red[3];
  q = red[4] + red[5] + red[6] + red[7];
  float mu = s * (1.0f / DMODEL);
  float var = q * (1.0f / DMODEL) - mu * mu;
  float rs = rsqrtf(var + 1e-5f);
  float4 wv4 = ((const float4*)w)[t];
  float4 bv4 = ((const float4*)b)[t];
  ushort4 o;
  o.x = f2bf((v.x - mu) * rs * wv4.x + bv4.x);
  o.y = f2bf((v.y - mu) * rs * wv4.y + bv4.y);
  o.z = f2bf((v.z - mu) * rs * wv4.z + bv4.z);
  o.w = f2bf((v.w - mu) * rs * wv4.w + bv4.w);
  ((ushort4*)(out + (size_t)row * DMODEL))[t] = o;
}

// ---------------- GEMM: A[M][K] bf16 x Bt[N][K] bf16, fp32 acc ------------
template <int EPI>
__global__ __launch_bounds__(256) void gemm_kernel(
    const unsigned short* __restrict__ A, const unsigned short* __restrict__ Bt,
    const float* __restrict__ bias, int N, int K,
    void* __restrict__ o0, void* __restrict__ o1, void* __restrict__ o2,
    const float* __restrict__ extra) {
  __shared__ __align__(16) unsigned short sA[128 * 32];
  __shared__ __align__(16) unsigned short sB[128 * 32];
  const int t = threadIdx.x;
  const int w = t >> 6, lane = t & 63;
  const int wr = w >> 1, wc = w & 1;

  // T1: bijective XCD-aware swizzle (m204); all grids here have nwg % 8 == 0
  const int gx = gridDim.x;
  const int nwg = gx * gridDim.y;
  int bid = blockIdx.y * gx + blockIdx.x;
  {
    int xcd = bid & 7, pos = bid >> 3;
    int qq = nwg >> 3, rr = nwg & 7;
    bid = (xcd < rr ? xcd * (qq + 1) : rr * (qq + 1) + (xcd - rr) * qq) + pos;
  }
  const int m0 = (bid / gx) * 128, n0 = (bid % gx) * 128;

  const int o0b = w * 2048 + lane * 16;
  const int o1b = o0b + 1024;
  const char* gA0 = (const char*)A + (size_t)(m0 + (o0b >> 6)) * K * 2 + (o0b & 63);
  const char* gA1 = (const char*)A + (size_t)(m0 + (o1b >> 6)) * K * 2 + (o1b & 63);
  const char* gB0 = (const char*)Bt + (size_t)(n0 + (o0b >> 6)) * K * 2 + (o0b & 63);
  const char* gB1 = (const char*)Bt + (size_t)(n0 + (o1b >> 6)) * K * 2 + (o1b & 63);
  char* lA = (char*)sA + w * 2048;
  char* lB = (char*)sB + w * 2048;

  f32x4 acc[4][4] = {};
  const int lc = lane & 15, lh = lane >> 4;
  const int aoff = (wr * 64 + lc) * 32 + lh * 8;
  const int boff = (wc * 64 + lc) * 32 + lh * 8;

  for (int k0 = 0; k0 < K; k0 += 32) {
    __syncthreads();
    GLOAD_LDS16(gA0 + (size_t)k0 * 2, lA);
    GLOAD_LDS16(gA1 + (size_t)k0 * 2, lA + 1024);
    GLOAD_LDS16(gB0 + (size_t)k0 * 2, lB);
    GLOAD_LDS16(gB1 + (size_t)k0 * 2, lB + 1024);
    __syncthreads();
    bf16x8 af[4], bg[4];
#pragma unroll
    for (int i = 0; i < 4; ++i) af[i] = *(const bf16x8*)(sA + aoff + i * 16 * 32);
#pragma unroll
    for (int i = 0; i < 4; ++i) bg[i] = *(const bf16x8*)(sB + boff + i * 16 * 32);
#pragma unroll
    for (int i = 0; i < 4; ++i)
#pragma unroll
      for (int j = 0; j < 4; ++j)
        acc[i][j] = __builtin_amdgcn_mfma_f32_16x16x32_bf16(af[i], bg[j], acc[i][j], 0, 0, 0);
  }

#pragma unroll
  for (int i = 0; i < 4; ++i)
#pragma unroll
    for (int j = 0; j < 4; ++j) {
      int col = n0 + wc * 64 + j * 16 + lc;
      float bcol = bias[col];
#pragma unroll
      for (int r = 0; r < 4; ++r) {
        int row = m0 + wr * 64 + i * 16 + lh * 4 + r;
        float val = acc[i][j][r] + bcol;
        if constexpr (EPI == 0) {
          int bb = row >> 11, srow = row & 2047;
          int hh = col / 192, rem = col - hh * 192;
          int which = rem >> 6, a = rem & 63;
          unsigned short* dst =
              which == 0 ? (unsigned short*)o0 : which == 1 ? (unsigned short*)o1 : (unsigned short*)o2;
          dst[(((size_t)bb * NHEAD + hh) * S_LEN + srow) * HDIM + a] = f2bf(val);
        } else if constexpr (EPI == 2) {
          float g = 0.5f * val * (1.0f + erff(val * 0.70710678118654752f));
          ((unsigned short*)o0)[(size_t)row * N + col] = f2bf(g);
        } else {
          size_t idx = (size_t)row * DMODEL + col;
          ((float*)o0)[idx] = val + extra[idx];
        }
      }
    }
}

// ---------------- causal flash attention, bf16, paired q-tiles ------------
// Block pi handles q-tiles {pi, 31-pi}: balanced 33 compute-units/block,
// K/V staged once for both. Softmax in exp2 domain.
// NOTE: no min-waves launch_bounds — round-2's (256,4) capped VGPRs at 64
// and spilled the dual-tile state to scratch (560 MB of spill writes).
__global__ __launch_bounds__(256) void attn_kernel(
    const unsigned short* __restrict__ Q, const unsigned short* __restrict__ Kk,
    const unsigned short* __restrict__ V, unsigned short* __restrict__ ctx) {
  __shared__ __align__(16) unsigned short sK[64 * 64];     // swizzled rows of 128B
  __shared__ __align__(16) unsigned short sVt[64 * 72];    // V^T, padded
  __shared__ __align__(16) unsigned short sP[4][16 * 72];  // per-wave P

  const int pi = blockIdx.x;     // 0..15
  const int bh = blockIdx.y;     // 0..63
  const int t = threadIdx.x;
  const int w = t >> 6, lane = t & 63;
  const int lc = lane & 15, lh = lane >> 4;
  const int qtA = pi, qtB = 31 - pi;
  const size_t base = (size_t)bh * S_LEN * HDIM;
  const unsigned short* Qb = Q + base;
  const unsigned short* Kb = Kk + base;
  const unsigned short* Vb = V + base;

  bf16x8 qfA[2], qfB[2];
  {
    const unsigned short* qa = Qb + (size_t)(qtA * 64 + w * 16 + lc) * HDIM;
    const unsigned short* qb = Qb + (size_t)(qtB * 64 + w * 16 + lc) * HDIM;
    qfA[0] = *(const bf16x8*)(qa + lh * 8);
    qfA[1] = *(const bf16x8*)(qa + 32 + lh * 8);
    qfB[0] = *(const bf16x8*)(qb + lh * 8);
    qfB[1] = *(const bf16x8*)(qb + 32 + lh * 8);
  }

  f32x4 accA[4] = {}, accB[4] = {};
  float mA[4], lA[4], mB[4], lB[4];
#pragma unroll
  for (int r = 0; r < 4; ++r) { mA[r] = -INFINITY; lA[r] = 0.f; mB[r] = -INFINITY; lB[r] = 0.f; }

  const float SCL = 0.125f * 1.44269504088896f;  // exp2 domain

  auto process = [&](const bf16x8 (&qf)[2], f32x4 (&acc)[4], float (&mrow)[4],
                     float (&lrow)[4], bool diag) {
    f32x4 s[4] = {};
    __builtin_amdgcn_s_setprio(1);
#pragma unroll
    for (int f = 0; f < 4; ++f) {
      int row = f * 16 + lc;
      int swz = (row & 7) << 4;
#pragma unroll
      for (int kk = 0; kk < 2; ++kk) {
        int cb = kk * 64 + lh * 16;
        bf16x8 kf = *(const bf16x8*)((const char*)sK + row * 128 + (cb ^ swz));
        s[f] = __builtin_amdgcn_mfma_f32_16x16x32_bf16(qf[kk], kf, s[f], 0, 0, 0);
      }
    }
    __builtin_amdgcn_s_setprio(0);
#pragma unroll
    for (int f = 0; f < 4; ++f)
#pragma unroll
      for (int r = 0; r < 4; ++r) {
        float sv = s[f][r] * SCL;
        if (diag && (f * 16 + lc > w * 16 + lh * 4 + r)) sv = -INFINITY;
        s[f][r] = sv;
      }
    float alpha[4];
#pragma unroll
    for (int r = 0; r < 4; ++r) {
      float mv = fmaxf(fmaxf(s[0][r], s[1][r]), fmaxf(s[2][r], s[3][r]));
#pragma unroll
      for (int msk = 1; msk < 16; msk <<= 1) mv = fmaxf(mv, __shfl_xor(mv, msk, 64));
      float mnew = fmaxf(mrow[r], mv);
      alpha[r] = __builtin_amdgcn_exp2f(mrow[r] - mnew);
      mrow[r] = mnew;
    }
#pragma unroll
    for (int r = 0; r < 4; ++r) {
      float ps = 0.f;
#pragma unroll
      for (int f = 0; f < 4; ++f) {
        float p = __builtin_amdgcn_exp2f(s[f][r] - mrow[r]);
        s[f][r] = p;
        ps += p;
      }
#pragma unroll
      for (int msk = 1; msk < 16; msk <<= 1) ps += __shfl_xor(ps, msk, 64);
      lrow[r] = lrow[r] * alpha[r] + ps;
#pragma unroll
      for (int f = 0; f < 4; ++f) acc[f][r] *= alpha[r];
    }
    unsigned short* Pw = &sP[w][0];
#pragma unroll
    for (int f = 0; f < 4; ++f)
#pragma unroll
      for (int r = 0; r < 4; ++r)
        Pw[(lh * 4 + r) * 72 + f * 16 + lc] = f2bf(s[f][r]);
    bf16x8 pa[2];
#pragma unroll
    for (int kk = 0; kk < 2; ++kk)
      pa[kk] = *(const bf16x8*)(Pw + lc * 72 + kk * 32 + lh * 8);
    __builtin_amdgcn_s_setprio(1);
#pragma unroll
    for (int f = 0; f < 4; ++f)
#pragma unroll
      for (int kk = 0; kk < 2; ++kk) {
        bf16x8 bv = *(const bf16x8*)(sVt + (f * 16 + lc) * 72 + kk * 32 + lh * 8);
        acc[f] = __builtin_amdgcn_mfma_f32_16x16x32_bf16(pa[kk], bv, acc[f], 0, 0, 0);
      }
    __builtin_amdgcn_s_setprio(0);
  };

  for (int tile = 0; tile <= qtB; ++tile) {
    const int kv0 = tile * 64;
    __syncthreads();
    {  // K stage: pre-swizzled global source, linear LDS dest (rule #21)
      const char* Ks = (const char*)(Kb + (size_t)kv0 * HDIM);
#pragma unroll
      for (int c = 0; c < 2; ++c) {
        int o = w * 2048 + c * 1024 + lane * 16;
        int row = o >> 7, cb = o & 127;
        int cbs = cb ^ ((row & 7) << 4);
        GLOAD_LDS16(Ks + row * 128 + cbs, (char*)sK + w * 2048 + c * 1024);
      }
    }
    {  // V^T stage: each wave owns d-block w*16, lanes sweep kv -> conflict-free
      const unsigned short* Vs = Vb + (size_t)kv0 * HDIM;
      const int d0 = w * 16;
      u16x8 v0 = *(const u16x8*)(Vs + (size_t)lane * HDIM + d0);
      u16x8 v1 = *(const u16x8*)(Vs + (size_t)lane * HDIM + d0 + 8);
#pragma unroll
      for (int j = 0; j < 8; ++j) sVt[(d0 + j) * 72 + lane] = (unsigned short)v0[j];
#pragma unroll
      for (int j = 0; j < 8; ++j) sVt[(d0 + 8 + j) * 72 + lane] = (unsigned short)v1[j];
    }
    __syncthreads();

    process(qfB, accB, mB, lB, tile == qtB);
    if (tile <= qtA) process(qfA, accA, mA, lA, tile == qtA);
  }

  const int b = bh >> 4, h = bh & 15;
  auto writeout = [&](int qt, f32x4 (&acc)[4], float (&lrow)[4]) {
#pragma unroll
    for (int r = 0; r < 4; ++r) {
      float inv = 1.0f / lrow[r];
      int qg = qt * 64 + w * 16 + lh * 4 + r;
#pragma unroll
      for (int f = 0; f < 4; ++f)
        ctx[((size_t)b * S_LEN + qg) * DMODEL + h * HDIM + f * 16 + lc] = f2bf(acc[f][r] * inv);
    }
  };
  writeout(qtA, accA, lA);
  writeout(qtB, accB, lB);
}

// ---------------- launch --------------------------------------------------
extern "C" void kernel_launch(void* const* d_in, const int* in_sizes, int n_in,
                              void* d_out, int out_size, void* d_ws, size_t ws_size,
                              hipStream_t stream) {
  const float* x    = (const float*)d_in[0];
  const float* ln1w = (const float*)d_in[1];
  const float* ln1b = (const float*)d_in[2];
  const float* ln2w = (const float*)d_in[3];
  const float* ln2b = (const float*)d_in[4];
  const float* Wqkv = (const float*)d_in[5];
  const float* bqkv = (const float*)d_in[6];
  const float* Wo   = (const float*)d_in[7];
  const float* bo   = (const float*)d_in[8];
  const float* Wup  = (const float*)d_in[9];
  const float* bup  = (const float*)d_in[10];
  const float* Wdn  = (const float*)d_in[11];
  const float* bdn  = (const float*)d_in[12];

  char* ws = (char*)d_ws;
  unsigned short* xn  = (unsigned short*)(ws + 0);
  unsigned short* qb  = (unsigned short*)(ws + 16777216);
  unsigned short* kb  = (unsigned short*)(ws + 33554432);
  unsigned short* vb  = (unsigned short*)(ws + 50331648);
  unsigned short* hb  = (unsigned short*)(ws + 0);
  unsigned short* ctx = (unsigned short*)(ws + 67108864);
  unsigned short* hn  = (unsigned short*)(ws + 67108864);
  float* attn         = (float*)(ws + 83886080);
  unsigned short* WtQKV = (unsigned short*)(ws + 117440512);
  unsigned short* WtO   = (unsigned short*)(ws + 123731968);
  unsigned short* WtUP  = (unsigned short*)(ws + 125829120);
  unsigned short* WtDN  = (unsigned short*)(ws + 134217728);

  dim3 tb(32, 8);
  wtrans_kernel<<<dim3(3072 / 32, 1024 / 32), tb, 0, stream>>>(Wqkv, WtQKV, 1024, 3072);
  wtrans_kernel<<<dim3(1024 / 32, 1024 / 32), tb, 0, stream>>>(Wo, WtO, 1024, 1024);
  wtrans_kernel<<<dim3(4096 / 32, 1024 / 32), tb, 0, stream>>>(Wup, WtUP, 1024, 4096);
  wtrans_kernel<<<dim3(1024 / 32, 4096 / 32), tb, 0, stream>>>(Wdn, WtDN, 4096, 1024);

  ln_kernel<<<8192, 256, 0, stream>>>(x, ln1w, ln1b, xn);

  gemm_kernel<0><<<dim3(3072 / 128, 8192 / 128), 256, 0, stream>>>(
      xn, WtQKV, bqkv, 3072, 1024, qb, kb, vb, nullptr);

  attn_kernel<<<dim3(16, 64), 256, 0, stream>>>(qb, kb, vb, ctx);

  gemm_kernel<1><<<dim3(1024 / 128, 8192 / 128), 256, 0, stream>>>(
      ctx, WtO, bo, 1024, 1024, attn, nullptr, nullptr, x);

  ln_kernel<<<8192, 256, 0, stream>>>(attn, ln2w, ln2b, hn);

  gemm_kernel<2><<<dim3(4096 / 128, 8192 / 128), 256, 0, stream>>>(
      hn, WtUP, bup, 4096, 1024, hb, nullptr, nullptr, nullptr);

  gemm_kernel<3><<<dim3(1024 / 128, 8192 / 128), 256, 0, stream>>>(
      hb, WtDN, bdn, 1024, 4096, d_out, nullptr, nullptr, attn);
}

// Round 5
// 615.245 us; speedup vs baseline: 1.2749x; 1.0217x over previous
//
#include <hip/hip_runtime.h>
#include <hip/hip_bf16.h>
#include <math.h>

#define S_LEN 2048
#define DMODEL 1024
#define NHEAD 16
#define HDIM 64

typedef __attribute__((ext_vector_type(8))) short bf16x8;
typedef __attribute__((ext_vector_type(4))) float f32x4;
typedef __attribute__((ext_vector_type(8))) unsigned short u16x8;

#define GLOAD_LDS16(g, l)                                                      \
  __builtin_amdgcn_global_load_lds(                                            \
      (const __attribute__((address_space(1))) void*)(g),                      \
      (__attribute__((address_space(3))) void*)(l), 16, 0, 0)

static __device__ __forceinline__ unsigned short f2bf(float f) {
  union { float f; unsigned int i; } u; u.f = f;
  unsigned int r = u.i + 0x7fff + ((u.i >> 16) & 1);
  return (unsigned short)(r >> 16);
}

// ---------------- weight transpose + cast: W[K][N] f32 -> Wt[N][K] bf16 ----
__global__ __launch_bounds__(256) void wtrans_kernel(const float* __restrict__ W,
                                                     unsigned short* __restrict__ Wt,
                                                     int K, int N) {
  __shared__ float tile[32][33];
  int tx = threadIdx.x, ty = threadIdx.y;
  int n0 = blockIdx.x * 32, k0 = blockIdx.y * 32;
#pragma unroll
  for (int i = 0; i < 4; ++i)
    tile[ty * 4 + i][tx] = W[(size_t)(k0 + ty * 4 + i) * N + n0 + tx];
  __syncthreads();
#pragma unroll
  for (int i = 0; i < 4; ++i)
    Wt[(size_t)(n0 + ty * 4 + i) * K + k0 + tx] = f2bf(tile[tx][ty * 4 + i]);
}

// ---------------- LayerNorm (fp32 in) -> bf16 out -------------------------
__global__ __launch_bounds__(256) void ln_kernel(const float* __restrict__ X,
                                                 const float* __restrict__ w,
                                                 const float* __restrict__ b,
                                                 unsigned short* __restrict__ out) {
  int row = blockIdx.x;
  int t = threadIdx.x;
  const float4* xr = (const float4*)(X + (size_t)row * DMODEL);
  float4 v = xr[t];
  float s = v.x + v.y + v.z + v.w;
  float q = v.x * v.x + v.y * v.y + v.z * v.z + v.w * v.w;
#pragma unroll
  for (int m = 1; m < 64; m <<= 1) {
    s += __shfl_xor(s, m, 64);
    q += __shfl_xor(q, m, 64);
  }
  __shared__ float red[8];
  int wv = t >> 6;
  if ((t & 63) == 0) { red[wv] = s; red[4 + wv] = q; }
  __syncthreads();
  s = red[0] + red[1] + red[2] + red[3];
  q = red[4] + red[5] + red[6] + red[7];
  float mu = s * (1.0f / DMODEL);
  float var = q * (1.0f / DMODEL) - mu * mu;
  float rs = rsqrtf(var + 1e-5f);
  float4 wv4 = ((const float4*)w)[t];
  float4 bv4 = ((const float4*)b)[t];
  ushort4 o;
  o.x = f2bf((v.x - mu) * rs * wv4.x + bv4.x);
  o.y = f2bf((v.y - mu) * rs * wv4.y + bv4.y);
  o.z = f2bf((v.z - mu) * rs * wv4.z + bv4.z);
  o.w = f2bf((v.w - mu) * rs * wv4.w + bv4.w);
  ((ushort4*)(out + (size_t)row * DMODEL))[t] = o;
}

// ======== 256x256 8-phase GEMM (T2 swizzle + T3/T4 counted vmcnt + T5) ====
// A[M][K] bf16 x Bt[N][K] bf16 -> C[256x256 tile], fp32 acc.
// 512 thr / 8 waves (2Mq x 4Nq within each 128x128 quadrant), BK=64.
// LDS 128 KiB: [buf][A|B][half][128 rows x 64 cols bf16], rows = 128 B,
// XOR-swizzled by ((row&7)<<4) via pre-swizzled global source (rule #21).
// Per K-tile: 4 phases = C-quadrants Q(mh,nh); each phase: 12x ds_read_b128,
// 2x global_load_lds (one half-tile of next K-tile), s_barrier, 16 MFMA
// (setprio-wrapped), counted vmcnt(4) at phase ends 0,1,3 (never 0), s_barrier.
// Staging order A0,B0,B1,A1 matches quadrant first-needs exactly.
// EPI: 0 = QKV scatter, 2 = gelu bf16 out (stride N).
template <int EPI>
__global__ __launch_bounds__(512, 2) void gemm256_kernel(
    const unsigned short* __restrict__ A, const unsigned short* __restrict__ Bt,
    const float* __restrict__ bias, int N, int K,
    void* __restrict__ o0, void* __restrict__ o1, void* __restrict__ o2) {
  __shared__ __align__(16) unsigned short lds[2][2][2][128 * 64];
  const int t = threadIdx.x;
  const int w = t >> 6, lane = t & 63;
  const int qr = w >> 2, qc = w & 3;
  const int lc = lane & 15, lh = lane >> 4;

  // T1: bijective XCD swizzle (nwg here: 384/512, both %8==0)
  const int gx = gridDim.x;
  const int nwg = gx * gridDim.y;
  int bid = blockIdx.y * gx + blockIdx.x;
  {
    int xcd = bid & 7, pos = bid >> 3;
    int qq = nwg >> 3, rr = nwg & 7;
    bid = (xcd < rr ? xcd * (qq + 1) : rr * (qq + 1) + (xcd - rr) * qq) + pos;
  }
  const int m0 = (bid / gx) * 256, n0 = (bid % gx) * 256;

  // staging addressing (lane-derived; swizzle folds to lane-only form)
  const int srow = lane >> 3;                 // 0..7
  const int scol = 16 * ((lane & 7) ^ srow);  // pre-swizzled byte col
  const size_t ld2 = (size_t)K * 2;
  const char* gA = (const char*)A + (size_t)(m0 + 16 * w + srow) * ld2 + scol;
  const char* gB = (const char*)Bt + (size_t)(n0 + 16 * w + srow) * ld2 + scol;
  const int ldsw = w * 1024;  // shorts: wave's 2 KiB staging slice within a half

  f32x4 acc[4][8] = {};  // [quadrant][fm*2+fn]

  const int sw = (lc & 7) << 4;
  const int NT = K >> 6;

  auto stage_half = [&](int buf, int mat, int half, int kt) {
    const char* g = (mat == 0 ? gA : gB) + (size_t)half * 128 * ld2 + (size_t)kt * 128;
    unsigned short* l = &lds[buf][mat][half][ldsw];
    GLOAD_LDS16(g, l);
    GLOAD_LDS16(g + 8 * ld2, (char*)l + 1024);
  };

  // prologue: stage tile 0 fully (order A0,B0,B1,A1), wait for A0+B0
  stage_half(0, 0, 0, 0);
  stage_half(0, 1, 0, 0);
  stage_half(0, 1, 1, 0);
  stage_half(0, 0, 1, 0);
  asm volatile("s_waitcnt vmcnt(4)" ::: "memory");
  __builtin_amdgcn_s_barrier();

  for (int kt = 0; kt < NT; ++kt) {
    const int cur = kt & 1;
    const int nkt = (kt + 1 < NT) ? kt + 1 : kt;  // last tile: harmless restage
#pragma unroll
    for (int ph = 0; ph < 4; ++ph) {
      const int mh = ph >> 1, nh = ph & 1;
      const unsigned short* ha = lds[cur][0][mh];
      const unsigned short* hb = lds[cur][1][nh];
      bf16x8 af[2][4], bf[2][2];
#pragma unroll
      for (int ks = 0; ks < 2; ++ks) {
        const int cc = ((ks << 6) | (lh << 4)) ^ sw;
#pragma unroll
        for (int fm = 0; fm < 4; ++fm)
          af[ks][fm] = *(const bf16x8*)((const char*)ha + (qr * 64 + fm * 16 + lc) * 128 + cc);
#pragma unroll
        for (int fn = 0; fn < 2; ++fn)
          bf[ks][fn] = *(const bf16x8*)((const char*)hb + (qc * 32 + fn * 16 + lc) * 128 + cc);
      }
      // stage next tile's half: ph 0->A0, 1->B0, 2->B1, 3->A1
      const int smat = (ph == 0 || ph == 3) ? 0 : 1;
      const int shalf = (ph >= 2) ? 1 : 0;
      stage_half(cur ^ 1, smat, shalf, nkt);
      __builtin_amdgcn_s_barrier();
      __builtin_amdgcn_s_setprio(1);
#pragma unroll
      for (int ks = 0; ks < 2; ++ks)
#pragma unroll
        for (int fm = 0; fm < 4; ++fm)
#pragma unroll
          for (int fn = 0; fn < 2; ++fn)
            acc[ph][fm * 2 + fn] = __builtin_amdgcn_mfma_f32_16x16x32_bf16(
                af[ks][fm], bf[ks][fn], acc[ph][fm * 2 + fn], 0, 0, 0);
      __builtin_amdgcn_s_setprio(0);
      if (ph != 2) asm volatile("s_waitcnt vmcnt(4)" ::: "memory");
      __builtin_amdgcn_s_barrier();
    }
  }

#pragma unroll
  for (int q = 0; q < 4; ++q) {
    const int mh = q >> 1, nh = q & 1;
#pragma unroll
    for (int fm = 0; fm < 4; ++fm)
#pragma unroll
      for (int fn = 0; fn < 2; ++fn) {
        int col = n0 + nh * 128 + qc * 32 + fn * 16 + lc;
        float bcol = bias[col];
#pragma unroll
        for (int r = 0; r < 4; ++r) {
          int row = m0 + mh * 128 + qr * 64 + fm * 16 + lh * 4 + r;
          float val = acc[q][fm * 2 + fn][r] + bcol;
          if constexpr (EPI == 0) {
            int bb = row >> 11, srw = row & 2047;
            int hh = col / 192, rem = col - hh * 192;
            int which = rem >> 6, a = rem & 63;
            unsigned short* dst =
                which == 0 ? (unsigned short*)o0 : which == 1 ? (unsigned short*)o1 : (unsigned short*)o2;
            dst[(((size_t)bb * NHEAD + hh) * S_LEN + srw) * HDIM + a] = f2bf(val);
          } else {
            float g = 0.5f * val * (1.0f + erff(val * 0.70710678118654752f));
            ((unsigned short*)o0)[(size_t)row * N + col] = f2bf(g);
          }
        }
      }
  }
}

// ---------------- GEMM: m97 128x128 (kept for N=1024 shapes) --------------
// EPI: 1/3 = fp32 out = acc + bias + extra (residual)
template <int EPI>
__global__ __launch_bounds__(256) void gemm_kernel(
    const unsigned short* __restrict__ A, const unsigned short* __restrict__ Bt,
    const float* __restrict__ bias, int N, int K,
    void* __restrict__ o0, const float* __restrict__ extra) {
  __shared__ __align__(16) unsigned short sA[128 * 32];
  __shared__ __align__(16) unsigned short sB[128 * 32];
  const int t = threadIdx.x;
  const int w = t >> 6, lane = t & 63;
  const int wr = w >> 1, wc = w & 1;

  const int gx = gridDim.x;
  const int nwg = gx * gridDim.y;
  int bid = blockIdx.y * gx + blockIdx.x;
  {
    int xcd = bid & 7, pos = bid >> 3;
    int qq = nwg >> 3, rr = nwg & 7;
    bid = (xcd < rr ? xcd * (qq + 1) : rr * (qq + 1) + (xcd - rr) * qq) + pos;
  }
  const int m0 = (bid / gx) * 128, n0 = (bid % gx) * 128;

  const int o0b = w * 2048 + lane * 16;
  const int o1b = o0b + 1024;
  const char* gA0 = (const char*)A + (size_t)(m0 + (o0b >> 6)) * K * 2 + (o0b & 63);
  const char* gA1 = (const char*)A + (size_t)(m0 + (o1b >> 6)) * K * 2 + (o1b & 63);
  const char* gB0 = (const char*)Bt + (size_t)(n0 + (o0b >> 6)) * K * 2 + (o0b & 63);
  const char* gB1 = (const char*)Bt + (size_t)(n0 + (o1b >> 6)) * K * 2 + (o1b & 63);
  char* lA = (char*)sA + w * 2048;
  char* lB = (char*)sB + w * 2048;

  f32x4 acc[4][4] = {};
  const int lc = lane & 15, lh = lane >> 4;
  const int aoff = (wr * 64 + lc) * 32 + lh * 8;
  const int boff = (wc * 64 + lc) * 32 + lh * 8;

  for (int k0 = 0; k0 < K; k0 += 32) {
    __syncthreads();
    GLOAD_LDS16(gA0 + (size_t)k0 * 2, lA);
    GLOAD_LDS16(gA1 + (size_t)k0 * 2, lA + 1024);
    GLOAD_LDS16(gB0 + (size_t)k0 * 2, lB);
    GLOAD_LDS16(gB1 + (size_t)k0 * 2, lB + 1024);
    __syncthreads();
    bf16x8 af[4], bg[4];
#pragma unroll
    for (int i = 0; i < 4; ++i) af[i] = *(const bf16x8*)(sA + aoff + i * 16 * 32);
#pragma unroll
    for (int i = 0; i < 4; ++i) bg[i] = *(const bf16x8*)(sB + boff + i * 16 * 32);
#pragma unroll
    for (int i = 0; i < 4; ++i)
#pragma unroll
      for (int j = 0; j < 4; ++j)
        acc[i][j] = __builtin_amdgcn_mfma_f32_16x16x32_bf16(af[i], bg[j], acc[i][j], 0, 0, 0);
  }

#pragma unroll
  for (int i = 0; i < 4; ++i)
#pragma unroll
    for (int j = 0; j < 4; ++j) {
      int col = n0 + wc * 64 + j * 16 + lc;
      float bcol = bias[col];
#pragma unroll
      for (int r = 0; r < 4; ++r) {
        int row = m0 + wr * 64 + i * 16 + lh * 4 + r;
        float val = acc[i][j][r] + bcol;
        size_t idx = (size_t)row * DMODEL + col;
        ((float*)o0)[idx] = val + extra[idx];
      }
    }
}

// ---------------- causal flash attention, bf16, paired q-tiles ------------
__global__ __launch_bounds__(256) void attn_kernel(
    const unsigned short* __restrict__ Q, const unsigned short* __restrict__ Kk,
    const unsigned short* __restrict__ V, unsigned short* __restrict__ ctx) {
  __shared__ __align__(16) unsigned short sK[64 * 64];
  __shared__ __align__(16) unsigned short sVt[64 * 72];
  __shared__ __align__(16) unsigned short sP[4][16 * 72];

  const int pi = blockIdx.x;
  const int bh = blockIdx.y;
  const int t = threadIdx.x;
  const int w = t >> 6, lane = t & 63;
  const int lc = lane & 15, lh = lane >> 4;
  const int qtA = pi, qtB = 31 - pi;
  const size_t base = (size_t)bh * S_LEN * HDIM;
  const unsigned short* Qb = Q + base;
  const unsigned short* Kb = Kk + base;
  const unsigned short* Vb = V + base;

  bf16x8 qfA[2], qfB[2];
  {
    const unsigned short* qa = Qb + (size_t)(qtA * 64 + w * 16 + lc) * HDIM;
    const unsigned short* qb = Qb + (size_t)(qtB * 64 + w * 16 + lc) * HDIM;
    qfA[0] = *(const bf16x8*)(qa + lh * 8);
    qfA[1] = *(const bf16x8*)(qa + 32 + lh * 8);
    qfB[0] = *(const bf16x8*)(qb + lh * 8);
    qfB[1] = *(const bf16x8*)(qb + 32 + lh * 8);
  }

  f32x4 accA[4] = {}, accB[4] = {};
  float mA[4], lA[4], mB[4], lB[4];
#pragma unroll
  for (int r = 0; r < 4; ++r) { mA[r] = -INFINITY; lA[r] = 0.f; mB[r] = -INFINITY; lB[r] = 0.f; }

  const float SCL = 0.125f * 1.44269504088896f;

  auto process = [&](const bf16x8 (&qf)[2], f32x4 (&acc)[4], float (&mrow)[4],
                     float (&lrow)[4], bool diag) {
    f32x4 s[4] = {};
    __builtin_amdgcn_s_setprio(1);
#pragma unroll
    for (int f = 0; f < 4; ++f) {
      int row = f * 16 + lc;
      int swz = (row & 7) << 4;
#pragma unroll
      for (int kk = 0; kk < 2; ++kk) {
        int cb = kk * 64 + lh * 16;
        bf16x8 kf = *(const bf16x8*)((const char*)sK + row * 128 + (cb ^ swz));
        s[f] = __builtin_amdgcn_mfma_f32_16x16x32_bf16(qf[kk], kf, s[f], 0, 0, 0);
      }
    }
    __builtin_amdgcn_s_setprio(0);
#pragma unroll
    for (int f = 0; f < 4; ++f)
#pragma unroll
      for (int r = 0; r < 4; ++r) {
        float sv = s[f][r] * SCL;
        if (diag && (f * 16 + lc > w * 16 + lh * 4 + r)) sv = -INFINITY;
        s[f][r] = sv;
      }
    float alpha[4];
#pragma unroll
    for (int r = 0; r < 4; ++r) {
      float mv = fmaxf(fmaxf(s[0][r], s[1][r]), fmaxf(s[2][r], s[3][r]));
#pragma unroll
      for (int msk = 1; msk < 16; msk <<= 1) mv = fmaxf(mv, __shfl_xor(mv, msk, 64));
      float mnew = fmaxf(mrow[r], mv);
      alpha[r] = __builtin_amdgcn_exp2f(mrow[r] - mnew);
      mrow[r] = mnew;
    }
#pragma unroll
    for (int r = 0; r < 4; ++r) {
      float ps = 0.f;
#pragma unroll
      for (int f = 0; f < 4; ++f) {
        float p = __builtin_amdgcn_exp2f(s[f][r] - mrow[r]);
        s[f][r] = p;
        ps += p;
      }
#pragma unroll
      for (int msk = 1; msk < 16; msk <<= 1) ps += __shfl_xor(ps, msk, 64);
      lrow[r] = lrow[r] * alpha[r] + ps;
#pragma unroll
      for (int f = 0; f < 4; ++f) acc[f][r] *= alpha[r];
    }
    unsigned short* Pw = &sP[w][0];
#pragma unroll
    for (int f = 0; f < 4; ++f)
#pragma unroll
      for (int r = 0; r < 4; ++r)
        Pw[(lh * 4 + r) * 72 + f * 16 + lc] = f2bf(s[f][r]);
    bf16x8 pa[2];
#pragma unroll
    for (int kk = 0; kk < 2; ++kk)
      pa[kk] = *(const bf16x8*)(Pw + lc * 72 + kk * 32 + lh * 8);
    __builtin_amdgcn_s_setprio(1);
#pragma unroll
    for (int f = 0; f < 4; ++f)
#pragma unroll
      for (int kk = 0; kk < 2; ++kk) {
        bf16x8 bv = *(const bf16x8*)(sVt + (f * 16 + lc) * 72 + kk * 32 + lh * 8);
        acc[f] = __builtin_amdgcn_mfma_f32_16x16x32_bf16(pa[kk], bv, acc[f], 0, 0, 0);
      }
    __builtin_amdgcn_s_setprio(0);
  };

  for (int tile = 0; tile <= qtB; ++tile) {
    const int kv0 = tile * 64;
    __syncthreads();
    {
      const char* Ks = (const char*)(Kb + (size_t)kv0 * HDIM);
#pragma unroll
      for (int c = 0; c < 2; ++c) {
        int o = w * 2048 + c * 1024 + lane * 16;
        int row = o >> 7, cb = o & 127;
        int cbs = cb ^ ((row & 7) << 4);
        GLOAD_LDS16(Ks + row * 128 + cbs, (char*)sK + w * 2048 + c * 1024);
      }
    }
    {
      const unsigned short* Vs = Vb + (size_t)kv0 * HDIM;
      const int d0 = w * 16;
      u16x8 v0 = *(const u16x8*)(Vs + (size_t)lane * HDIM + d0);
      u16x8 v1 = *(const u16x8*)(Vs + (size_t)lane * HDIM + d0 + 8);
#pragma unroll
      for (int j = 0; j < 8; ++j) sVt[(d0 + j) * 72 + lane] = (unsigned short)v0[j];
#pragma unroll
      for (int j = 0; j < 8; ++j) sVt[(d0 + 8 + j) * 72 + lane] = (unsigned short)v1[j];
    }
    __syncthreads();

    process(qfB, accB, mB, lB, tile == qtB);
    if (tile <= qtA) process(qfA, accA, mA, lA, tile == qtA);
  }

  const int b = bh >> 4, h = bh & 15;
  auto writeout = [&](int qt, f32x4 (&acc)[4], float (&lrow)[4]) {
#pragma unroll
    for (int r = 0; r < 4; ++r) {
      float inv = 1.0f / lrow[r];
      int qg = qt * 64 + w * 16 + lh * 4 + r;
#pragma unroll
      for (int f = 0; f < 4; ++f)
        ctx[((size_t)b * S_LEN + qg) * DMODEL + h * HDIM + f * 16 + lc] = f2bf(acc[f][r] * inv);
    }
  };
  writeout(qtA, accA, lA);
  writeout(qtB, accB, lB);
}

// ---------------- launch --------------------------------------------------
extern "C" void kernel_launch(void* const* d_in, const int* in_sizes, int n_in,
                              void* d_out, int out_size, void* d_ws, size_t ws_size,
                              hipStream_t stream) {
  const float* x    = (const float*)d_in[0];
  const float* ln1w = (const float*)d_in[1];
  const float* ln1b = (const float*)d_in[2];
  const float* ln2w = (const float*)d_in[3];
  const float* ln2b = (const float*)d_in[4];
  const float* Wqkv = (const float*)d_in[5];
  const float* bqkv = (const float*)d_in[6];
  const float* Wo   = (const float*)d_in[7];
  const float* bo   = (const float*)d_in[8];
  const float* Wup  = (const float*)d_in[9];
  const float* bup  = (const float*)d_in[10];
  const float* Wdn  = (const float*)d_in[11];
  const float* bdn  = (const float*)d_in[12];

  char* ws = (char*)d_ws;
  unsigned short* xn  = (unsigned short*)(ws + 0);
  unsigned short* qb  = (unsigned short*)(ws + 16777216);
  unsigned short* kb  = (unsigned short*)(ws + 33554432);
  unsigned short* vb  = (unsigned short*)(ws + 50331648);
  unsigned short* hb  = (unsigned short*)(ws + 0);
  unsigned short* ctx = (unsigned short*)(ws + 67108864);
  unsigned short* hn  = (unsigned short*)(ws + 67108864);
  float* attn         = (float*)(ws + 83886080);
  unsigned short* WtQKV = (unsigned short*)(ws + 117440512);
  unsigned short* WtO   = (unsigned short*)(ws + 123731968);
  unsigned short* WtUP  = (unsigned short*)(ws + 125829120);
  unsigned short* WtDN  = (unsigned short*)(ws + 134217728);

  dim3 tb(32, 8);
  wtrans_kernel<<<dim3(3072 / 32, 1024 / 32), tb, 0, stream>>>(Wqkv, WtQKV, 1024, 3072);
  wtrans_kernel<<<dim3(1024 / 32, 1024 / 32), tb, 0, stream>>>(Wo, WtO, 1024, 1024);
  wtrans_kernel<<<dim3(4096 / 32, 1024 / 32), tb, 0, stream>>>(Wup, WtUP, 1024, 4096);
  wtrans_kernel<<<dim3(1024 / 32, 4096 / 32), tb, 0, stream>>>(Wdn, WtDN, 4096, 1024);

  ln_kernel<<<8192, 256, 0, stream>>>(x, ln1w, ln1b, xn);

  gemm256_kernel<0><<<dim3(3072 / 256, 8192 / 256), 512, 0, stream>>>(
      xn, WtQKV, bqkv, 3072, 1024, qb, kb, vb);

  attn_kernel<<<dim3(16, 64), 256, 0, stream>>>(qb, kb, vb, ctx);

  gemm_kernel<1><<<dim3(1024 / 128, 8192 / 128), 256, 0, stream>>>(
      ctx, WtO, bo, 1024, 1024, attn, x);

  ln_kernel<<<8192, 256, 0, stream>>>(attn, ln2w, ln2b, hn);

  gemm256_kernel<2><<<dim3(4096 / 256, 8192 / 256), 512, 0, stream>>>(
      hn, WtUP, bup, 4096, 1024, hb, nullptr, nullptr);

  gemm_kernel<3><<<dim3(1024 / 128, 8192 / 128), 256, 0, stream>>>(
      hb, WtDN, bdn, 1024, 4096, d_out, attn);
}

// Round 6
// 583.623 us; speedup vs baseline: 1.3440x; 1.0542x over previous
//
#include <hip/hip_runtime.h>
#include <hip/hip_bf16.h>
#include <math.h>

#define S_LEN 2048
#define DMODEL 1024
#define NHEAD 16
#define HDIM 64

typedef __attribute__((ext_vector_type(8))) short bf16x8;
typedef __attribute__((ext_vector_type(4))) float f32x4;
typedef __attribute__((ext_vector_type(8))) unsigned short u16x8;

#define GLOAD_LDS16(g, l)                                                      \
  __builtin_amdgcn_global_load_lds(                                            \
      (const __attribute__((address_space(1))) void*)(g),                      \
      (__attribute__((address_space(3))) void*)(l), 16, 0, 0)

static __device__ __forceinline__ unsigned short f2bf(float f) {
  union { float f; unsigned int i; } u; u.f = f;
  unsigned int r = u.i + 0x7fff + ((u.i >> 16) & 1);
  return (unsigned short)(r >> 16);
}

// ---------------- weight transpose + cast: W[K][N] f32 -> Wt[N][K] bf16 ----
__global__ __launch_bounds__(256) void wtrans_kernel(const float* __restrict__ W,
                                                     unsigned short* __restrict__ Wt,
                                                     int K, int N) {
  __shared__ float tile[32][33];
  int tx = threadIdx.x, ty = threadIdx.y;
  int n0 = blockIdx.x * 32, k0 = blockIdx.y * 32;
#pragma unroll
  for (int i = 0; i < 4; ++i)
    tile[ty * 4 + i][tx] = W[(size_t)(k0 + ty * 4 + i) * N + n0 + tx];
  __syncthreads();
#pragma unroll
  for (int i = 0; i < 4; ++i)
    Wt[(size_t)(n0 + ty * 4 + i) * K + k0 + tx] = f2bf(tile[tx][ty * 4 + i]);
}

// ---------------- LayerNorm (fp32 in) -> bf16 out -------------------------
__global__ __launch_bounds__(256) void ln_kernel(const float* __restrict__ X,
                                                 const float* __restrict__ w,
                                                 const float* __restrict__ b,
                                                 unsigned short* __restrict__ out) {
  int row = blockIdx.x;
  int t = threadIdx.x;
  const float4* xr = (const float4*)(X + (size_t)row * DMODEL);
  float4 v = xr[t];
  float s = v.x + v.y + v.z + v.w;
  float q = v.x * v.x + v.y * v.y + v.z * v.z + v.w * v.w;
#pragma unroll
  for (int m = 1; m < 64; m <<= 1) {
    s += __shfl_xor(s, m, 64);
    q += __shfl_xor(q, m, 64);
  }
  __shared__ float red[8];
  int wv = t >> 6;
  if ((t & 63) == 0) { red[wv] = s; red[4 + wv] = q; }
  __syncthreads();
  s = red[0] + red[1] + red[2] + red[3];
  q = red[4] + red[5] + red[6] + red[7];
  float mu = s * (1.0f / DMODEL);
  float var = q * (1.0f / DMODEL) - mu * mu;
  float rs = rsqrtf(var + 1e-5f);
  float4 wv4 = ((const float4*)w)[t];
  float4 bv4 = ((const float4*)b)[t];
  ushort4 o;
  o.x = f2bf((v.x - mu) * rs * wv4.x + bv4.x);
  o.y = f2bf((v.y - mu) * rs * wv4.y + bv4.y);
  o.z = f2bf((v.z - mu) * rs * wv4.z + bv4.z);
  o.w = f2bf((v.w - mu) * rs * wv4.w + bv4.w);
  ((ushort4*)(out + (size_t)row * DMODEL))[t] = o;
}

// ======== 256x256 8-phase GEMM (T2 swizzle + T3/T4 counted vmcnt + T5) ====
template <int EPI>
__global__ __launch_bounds__(512, 2) void gemm256_kernel(
    const unsigned short* __restrict__ A, const unsigned short* __restrict__ Bt,
    const float* __restrict__ bias, int N, int K,
    void* __restrict__ o0, void* __restrict__ o1, void* __restrict__ o2) {
  __shared__ __align__(16) unsigned short lds[2][2][2][128 * 64];
  const int t = threadIdx.x;
  const int w = t >> 6, lane = t & 63;
  const int qr = w >> 2, qc = w & 3;
  const int lc = lane & 15, lh = lane >> 4;

  const int gx = gridDim.x;
  const int nwg = gx * gridDim.y;
  int bid = blockIdx.y * gx + blockIdx.x;
  {
    int xcd = bid & 7, pos = bid >> 3;
    int qq = nwg >> 3, rr = nwg & 7;
    bid = (xcd < rr ? xcd * (qq + 1) : rr * (qq + 1) + (xcd - rr) * qq) + pos;
  }
  const int m0 = (bid / gx) * 256, n0 = (bid % gx) * 256;

  const int srow = lane >> 3;
  const int scol = 16 * ((lane & 7) ^ srow);
  const size_t ld2 = (size_t)K * 2;
  const char* gA = (const char*)A + (size_t)(m0 + 16 * w + srow) * ld2 + scol;
  const char* gB = (const char*)Bt + (size_t)(n0 + 16 * w + srow) * ld2 + scol;
  const int ldsw = w * 1024;

  f32x4 acc[4][8] = {};

  const int sw = (lc & 7) << 4;
  const int NT = K >> 6;

  auto stage_half = [&](int buf, int mat, int half, int kt) {
    const char* g = (mat == 0 ? gA : gB) + (size_t)half * 128 * ld2 + (size_t)kt * 128;
    unsigned short* l = &lds[buf][mat][half][ldsw];
    GLOAD_LDS16(g, l);
    GLOAD_LDS16(g + 8 * ld2, (char*)l + 1024);
  };

  stage_half(0, 0, 0, 0);
  stage_half(0, 1, 0, 0);
  stage_half(0, 1, 1, 0);
  stage_half(0, 0, 1, 0);
  asm volatile("s_waitcnt vmcnt(4)" ::: "memory");
  __builtin_amdgcn_s_barrier();

  for (int kt = 0; kt < NT; ++kt) {
    const int cur = kt & 1;
    const int nkt = (kt + 1 < NT) ? kt + 1 : kt;
#pragma unroll
    for (int ph = 0; ph < 4; ++ph) {
      const int mh = ph >> 1, nh = ph & 1;
      const unsigned short* ha = lds[cur][0][mh];
      const unsigned short* hb = lds[cur][1][nh];
      bf16x8 af[2][4], bf[2][2];
#pragma unroll
      for (int ks = 0; ks < 2; ++ks) {
        const int cc = ((ks << 6) | (lh << 4)) ^ sw;
#pragma unroll
        for (int fm = 0; fm < 4; ++fm)
          af[ks][fm] = *(const bf16x8*)((const char*)ha + (qr * 64 + fm * 16 + lc) * 128 + cc);
#pragma unroll
        for (int fn = 0; fn < 2; ++fn)
          bf[ks][fn] = *(const bf16x8*)((const char*)hb + (qc * 32 + fn * 16 + lc) * 128 + cc);
      }
      const int smat = (ph == 0 || ph == 3) ? 0 : 1;
      const int shalf = (ph >= 2) ? 1 : 0;
      stage_half(cur ^ 1, smat, shalf, nkt);
      __builtin_amdgcn_s_barrier();
      __builtin_amdgcn_s_setprio(1);
#pragma unroll
      for (int ks = 0; ks < 2; ++ks)
#pragma unroll
        for (int fm = 0; fm < 4; ++fm)
#pragma unroll
          for (int fn = 0; fn < 2; ++fn)
            acc[ph][fm * 2 + fn] = __builtin_amdgcn_mfma_f32_16x16x32_bf16(
                af[ks][fm], bf[ks][fn], acc[ph][fm * 2 + fn], 0, 0, 0);
      __builtin_amdgcn_s_setprio(0);
      if (ph != 2) asm volatile("s_waitcnt vmcnt(4)" ::: "memory");
      __builtin_amdgcn_s_barrier();
    }
  }

#pragma unroll
  for (int q = 0; q < 4; ++q) {
    const int mh = q >> 1, nh = q & 1;
#pragma unroll
    for (int fm = 0; fm < 4; ++fm)
#pragma unroll
      for (int fn = 0; fn < 2; ++fn) {
        int col = n0 + nh * 128 + qc * 32 + fn * 16 + lc;
        float bcol = bias[col];
#pragma unroll
        for (int r = 0; r < 4; ++r) {
          int row = m0 + mh * 128 + qr * 64 + fm * 16 + lh * 4 + r;
          float val = acc[q][fm * 2 + fn][r] + bcol;
          if constexpr (EPI == 0) {
            int bb = row >> 11, srw = row & 2047;
            int hh = col / 192, rem = col - hh * 192;
            int which = rem >> 6, a = rem & 63;
            unsigned short* dst =
                which == 0 ? (unsigned short*)o0 : which == 1 ? (unsigned short*)o1 : (unsigned short*)o2;
            dst[(((size_t)bb * NHEAD + hh) * S_LEN + srw) * HDIM + a] = f2bf(val);
          } else {
            float g = 0.5f * val * (1.0f + erff(val * 0.70710678118654752f));
            ((unsigned short*)o0)[(size_t)row * N + col] = f2bf(g);
          }
        }
      }
  }
}

// ---------------- GEMM: m97 128x128 (kept for N=1024 shapes) --------------
template <int EPI>
__global__ __launch_bounds__(256) void gemm_kernel(
    const unsigned short* __restrict__ A, const unsigned short* __restrict__ Bt,
    const float* __restrict__ bias, int N, int K,
    void* __restrict__ o0, const float* __restrict__ extra) {
  __shared__ __align__(16) unsigned short sA[128 * 32];
  __shared__ __align__(16) unsigned short sB[128 * 32];
  const int t = threadIdx.x;
  const int w = t >> 6, lane = t & 63;
  const int wr = w >> 1, wc = w & 1;

  const int gx = gridDim.x;
  const int nwg = gx * gridDim.y;
  int bid = blockIdx.y * gx + blockIdx.x;
  {
    int xcd = bid & 7, pos = bid >> 3;
    int qq = nwg >> 3, rr = nwg & 7;
    bid = (xcd < rr ? xcd * (qq + 1) : rr * (qq + 1) + (xcd - rr) * qq) + pos;
  }
  const int m0 = (bid / gx) * 128, n0 = (bid % gx) * 128;

  const int o0b = w * 2048 + lane * 16;
  const int o1b = o0b + 1024;
  const char* gA0 = (const char*)A + (size_t)(m0 + (o0b >> 6)) * K * 2 + (o0b & 63);
  const char* gA1 = (const char*)A + (size_t)(m0 + (o1b >> 6)) * K * 2 + (o1b & 63);
  const char* gB0 = (const char*)Bt + (size_t)(n0 + (o0b >> 6)) * K * 2 + (o0b & 63);
  const char* gB1 = (const char*)Bt + (size_t)(n0 + (o1b >> 6)) * K * 2 + (o1b & 63);
  char* lA = (char*)sA + w * 2048;
  char* lB = (char*)sB + w * 2048;

  f32x4 acc[4][4] = {};
  const int lc = lane & 15, lh = lane >> 4;
  const int aoff = (wr * 64 + lc) * 32 + lh * 8;
  const int boff = (wc * 64 + lc) * 32 + lh * 8;

  for (int k0 = 0; k0 < K; k0 += 32) {
    __syncthreads();
    GLOAD_LDS16(gA0 + (size_t)k0 * 2, lA);
    GLOAD_LDS16(gA1 + (size_t)k0 * 2, lA + 1024);
    GLOAD_LDS16(gB0 + (size_t)k0 * 2, lB);
    GLOAD_LDS16(gB1 + (size_t)k0 * 2, lB + 1024);
    __syncthreads();
    bf16x8 af[4], bg[4];
#pragma unroll
    for (int i = 0; i < 4; ++i) af[i] = *(const bf16x8*)(sA + aoff + i * 16 * 32);
#pragma unroll
    for (int i = 0; i < 4; ++i) bg[i] = *(const bf16x8*)(sB + boff + i * 16 * 32);
#pragma unroll
    for (int i = 0; i < 4; ++i)
#pragma unroll
      for (int j = 0; j < 4; ++j)
        acc[i][j] = __builtin_amdgcn_mfma_f32_16x16x32_bf16(af[i], bg[j], acc[i][j], 0, 0, 0);
  }

#pragma unroll
  for (int i = 0; i < 4; ++i)
#pragma unroll
    for (int j = 0; j < 4; ++j) {
      int col = n0 + wc * 64 + j * 16 + lc;
      float bcol = bias[col];
#pragma unroll
      for (int r = 0; r < 4; ++r) {
        int row = m0 + wr * 64 + i * 16 + lh * 4 + r;
        float val = acc[i][j][r] + bcol;
        size_t idx = (size_t)row * DMODEL + col;
        ((float*)o0)[idx] = val + extra[idx];
      }
    }
}

// ---------------- causal flash attention, swapped-QK^T softmax ------------
// s = mfma(K_frag, Q_frag): each lane owns P[q=lc][kv=f*16+lh*4+r] -> row
// reductions are in-lane + 2 shfl_xor (16,32); m/l are per-lane scalars.
// P->A-frag relayout via per-wave u32 LDS grid [q=lc][kvpair], stride 36.
__global__ __launch_bounds__(256) void attn_kernel(
    const unsigned short* __restrict__ Q, const unsigned short* __restrict__ Kk,
    const unsigned short* __restrict__ V, unsigned short* __restrict__ ctx) {
  __shared__ __align__(16) unsigned short sK[64 * 64];
  __shared__ __align__(16) unsigned short sVt[64 * 72];
  __shared__ __align__(16) unsigned int sPu[4][16 * 36];

  const int pi = blockIdx.x;
  const int bh = blockIdx.y;
  const int t = threadIdx.x;
  const int w = t >> 6, lane = t & 63;
  const int lc = lane & 15, lh = lane >> 4;
  const int qtA = pi, qtB = 31 - pi;
  const size_t base = (size_t)bh * S_LEN * HDIM;
  const unsigned short* Qb = Q + base;
  const unsigned short* Kb = Kk + base;
  const unsigned short* Vb = V + base;

  bf16x8 qfA[2], qfB[2];
  {
    const unsigned short* qa = Qb + (size_t)(qtA * 64 + w * 16 + lc) * HDIM;
    const unsigned short* qb = Qb + (size_t)(qtB * 64 + w * 16 + lc) * HDIM;
    qfA[0] = *(const bf16x8*)(qa + lh * 8);
    qfA[1] = *(const bf16x8*)(qa + 32 + lh * 8);
    qfB[0] = *(const bf16x8*)(qb + lh * 8);
    qfB[1] = *(const bf16x8*)(qb + 32 + lh * 8);
  }

  f32x4 accA[4] = {}, accB[4] = {};
  float mA = -INFINITY, lA = 0.f, mB = -INFINITY, lB = 0.f;

  const float SCL = 0.125f * 1.44269504088896f;

  auto process = [&](const bf16x8 (&qf)[2], f32x4 (&acc)[4], float& mrow,
                     float& lrow, bool diag) {
    f32x4 s[4] = {};
    __builtin_amdgcn_s_setprio(1);
#pragma unroll
    for (int f = 0; f < 4; ++f) {
      int row = f * 16 + lc;  // kv row (A operand)
      int swz = (row & 7) << 4;
#pragma unroll
      for (int kk = 0; kk < 2; ++kk) {
        int cb = kk * 64 + lh * 16;
        bf16x8 kf = *(const bf16x8*)((const char*)sK + row * 128 + (cb ^ swz));
        s[f] = __builtin_amdgcn_mfma_f32_16x16x32_bf16(kf, qf[kk], s[f], 0, 0, 0);
      }
    }
    __builtin_amdgcn_s_setprio(0);
    // scale + causal mask; lane holds P[q=lc][kv=f*16+lh*4+r]
#pragma unroll
    for (int f = 0; f < 4; ++f)
#pragma unroll
      for (int r = 0; r < 4; ++r) {
        float sv = s[f][r] * SCL;
        if (diag && (f * 16 + lh * 4 + r > w * 16 + lc)) sv = -INFINITY;
        s[f][r] = sv;
      }
    // row max: 15 in-lane + 2 cross-lane
    float mv = s[0][0];
#pragma unroll
    for (int f = 0; f < 4; ++f)
#pragma unroll
      for (int r = 0; r < 4; ++r) mv = fmaxf(mv, s[f][r]);
    mv = fmaxf(mv, __shfl_xor(mv, 16, 64));
    mv = fmaxf(mv, __shfl_xor(mv, 32, 64));
    float mnew = fmaxf(mrow, mv);
    float alpha = __builtin_amdgcn_exp2f(mrow - mnew);
    mrow = mnew;
    float ps = 0.f;
#pragma unroll
    for (int f = 0; f < 4; ++f)
#pragma unroll
      for (int r = 0; r < 4; ++r) {
        float p = __builtin_amdgcn_exp2f(s[f][r] - mnew);
        s[f][r] = p;
        ps += p;
      }
    ps += __shfl_xor(ps, 16, 64);
    ps += __shfl_xor(ps, 32, 64);
    lrow = lrow * alpha + ps;
    // P -> A-frag via per-wave LDS u32 grid (write b64 x4, read b128 x2)
    unsigned int* Pw = &sPu[w][0];
#pragma unroll
    for (int f = 0; f < 4; ++f) {
      uint2 wd;
      wd.x = (unsigned)f2bf(s[f][0]) | ((unsigned)f2bf(s[f][1]) << 16);
      wd.y = (unsigned)f2bf(s[f][2]) | ((unsigned)f2bf(s[f][3]) << 16);
      *(uint2*)&Pw[lc * 36 + f * 8 + lh * 2] = wd;
    }
    bf16x8 pa[2];
#pragma unroll
    for (int kk = 0; kk < 2; ++kk)
      pa[kk] = *(const bf16x8*)&Pw[lc * 36 + kk * 16 + lh * 4];
    // alpha broadcast to C-layout rows (q = lh*4+r), then rescale acc
    float al[4];
#pragma unroll
    for (int r = 0; r < 4; ++r) al[r] = __shfl(alpha, lh * 4 + r, 16);
#pragma unroll
    for (int f = 0; f < 4; ++f)
#pragma unroll
      for (int r = 0; r < 4; ++r) acc[f][r] *= al[r];
    __builtin_amdgcn_s_setprio(1);
#pragma unroll
    for (int f = 0; f < 4; ++f)
#pragma unroll
      for (int kk = 0; kk < 2; ++kk) {
        bf16x8 bv = *(const bf16x8*)(sVt + (f * 16 + lc) * 72 + kk * 32 + lh * 8);
        acc[f] = __builtin_amdgcn_mfma_f32_16x16x32_bf16(pa[kk], bv, acc[f], 0, 0, 0);
      }
    __builtin_amdgcn_s_setprio(0);
  };

  for (int tile = 0; tile <= qtB; ++tile) {
    const int kv0 = tile * 64;
    __syncthreads();
    {  // K stage: pre-swizzled global source, linear LDS dest (rule #21)
      const char* Ks = (const char*)(Kb + (size_t)kv0 * HDIM);
#pragma unroll
      for (int c = 0; c < 2; ++c) {
        int o = w * 2048 + c * 1024 + lane * 16;
        int row = o >> 7, cb = o & 127;
        int cbs = cb ^ ((row & 7) << 4);
        GLOAD_LDS16(Ks + row * 128 + cbs, (char*)sK + w * 2048 + c * 1024);
      }
    }
    {  // V^T stage: wave owns d-block w*16, lanes sweep kv -> conflict-free
      const unsigned short* Vs = Vb + (size_t)kv0 * HDIM;
      const int d0 = w * 16;
      u16x8 v0 = *(const u16x8*)(Vs + (size_t)lane * HDIM + d0);
      u16x8 v1 = *(const u16x8*)(Vs + (size_t)lane * HDIM + d0 + 8);
#pragma unroll
      for (int j = 0; j < 8; ++j) sVt[(d0 + j) * 72 + lane] = (unsigned short)v0[j];
#pragma unroll
      for (int j = 0; j < 8; ++j) sVt[(d0 + 8 + j) * 72 + lane] = (unsigned short)v1[j];
    }
    __syncthreads();

    process(qfB, accB, mB, lB, tile == qtB);
    if (tile <= qtA) process(qfA, accA, mA, lA, tile == qtA);
  }

  const int b = bh >> 4, h = bh & 15;
  auto writeout = [&](int qt, f32x4 (&acc)[4], float lrow) {
    float inv = 1.0f / lrow;
    float invr[4];
#pragma unroll
    for (int r = 0; r < 4; ++r) invr[r] = __shfl(inv, lh * 4 + r, 16);
#pragma unroll
    for (int r = 0; r < 4; ++r) {
      int qg = qt * 64 + w * 16 + lh * 4 + r;
#pragma unroll
      for (int f = 0; f < 4; ++f)
        ctx[((size_t)b * S_LEN + qg) * DMODEL + h * HDIM + f * 16 + lc] =
            f2bf(acc[f][r] * invr[r]);
    }
  };
  writeout(qtA, accA, lA);
  writeout(qtB, accB, lB);
}

// ---------------- launch --------------------------------------------------
extern "C" void kernel_launch(void* const* d_in, const int* in_sizes, int n_in,
                              void* d_out, int out_size, void* d_ws, size_t ws_size,
                              hipStream_t stream) {
  const float* x    = (const float*)d_in[0];
  const float* ln1w = (const float*)d_in[1];
  const float* ln1b = (const float*)d_in[2];
  const float* ln2w = (const float*)d_in[3];
  const float* ln2b = (const float*)d_in[4];
  const float* Wqkv = (const float*)d_in[5];
  const float* bqkv = (const float*)d_in[6];
  const float* Wo   = (const float*)d_in[7];
  const float* bo   = (const float*)d_in[8];
  const float* Wup  = (const float*)d_in[9];
  const float* bup  = (const float*)d_in[10];
  const float* Wdn  = (const float*)d_in[11];
  const float* bdn  = (const float*)d_in[12];

  char* ws = (char*)d_ws;
  unsigned short* xn  = (unsigned short*)(ws + 0);
  unsigned short* qb  = (unsigned short*)(ws + 16777216);
  unsigned short* kb  = (unsigned short*)(ws + 33554432);
  unsigned short* vb  = (unsigned short*)(ws + 50331648);
  unsigned short* hb  = (unsigned short*)(ws + 0);
  unsigned short* ctx = (unsigned short*)(ws + 67108864);
  unsigned short* hn  = (unsigned short*)(ws + 67108864);
  float* attn         = (float*)(ws + 83886080);
  unsigned short* WtQKV = (unsigned short*)(ws + 117440512);
  unsigned short* WtO   = (unsigned short*)(ws + 123731968);
  unsigned short* WtUP  = (unsigned short*)(ws + 125829120);
  unsigned short* WtDN  = (unsigned short*)(ws + 134217728);

  dim3 tb(32, 8);
  wtrans_kernel<<<dim3(3072 / 32, 1024 / 32), tb, 0, stream>>>(Wqkv, WtQKV, 1024, 3072);
  wtrans_kernel<<<dim3(1024 / 32, 1024 / 32), tb, 0, stream>>>(Wo, WtO, 1024, 1024);
  wtrans_kernel<<<dim3(4096 / 32, 1024 / 32), tb, 0, stream>>>(Wup, WtUP, 1024, 4096);
  wtrans_kernel<<<dim3(1024 / 32, 4096 / 32), tb, 0, stream>>>(Wdn, WtDN, 4096, 1024);

  ln_kernel<<<8192, 256, 0, stream>>>(x, ln1w, ln1b, xn);

  gemm256_kernel<0><<<dim3(3072 / 256, 8192 / 256), 512, 0, stream>>>(
      xn, WtQKV, bqkv, 3072, 1024, qb, kb, vb);

  attn_kernel<<<dim3(16, 64), 256, 0, stream>>>(qb, kb, vb, ctx);

  gemm_kernel<1><<<dim3(1024 / 128, 8192 / 128), 256, 0, stream>>>(
      ctx, WtO, bo, 1024, 1024, attn, x);

  ln_kernel<<<8192, 256, 0, stream>>>(attn, ln2w, ln2b, hn);

  gemm256_kernel<2><<<dim3(4096 / 256, 8192 / 256), 512, 0, stream>>>(
      hn, WtUP, bup, 4096, 1024, hb, nullptr, nullptr);

  gemm_kernel<3><<<dim3(1024 / 128, 8192 / 128), 256, 0, stream>>>(
      hb, WtDN, bdn, 1024, 4096, d_out, attn);
}